// Round 6
// baseline (7885.838 us; speedup 1.0000x reference)
//
#include <hip/hip_runtime.h>
#include <hip/hip_bf16.h>
#include <math.h>

// Problem constants
#define Sn 3
#define Hn 64
#define Dn 12
#define Bn 512
#define Ln 512
#define BC 2            // batch elems per workgroup
#define IN0 76          // D + H
#define NIN 22
#define CT 32           // timesteps per chunk
#define NCHUNK (Ln / CT)

using bf16 = __hip_bfloat16;

__device__ __forceinline__ float u2f(unsigned short x) {
    return __uint_as_float(((unsigned int)x) << 16);
}
__device__ __forceinline__ unsigned short f2u(float f) {
    bf16 h = __float2bfloat16(f);
    unsigned short u;
    __builtin_memcpy(&u, &h, 2);
    return u;
}
__device__ __forceinline__ float sigm(float x) { return 1.0f / (1.0f + expf(-x)); }
__device__ __forceinline__ float gelu_ex(float x) { return 0.5f * x * (1.0f + erff(x * 0.70710678118654752f)); }
// bank-pad: insert 4 floats of pad every 16 (keeps 16-float blocks contiguous/16B-aligned)
__device__ __forceinline__ int padi(int c) { return c + ((c >> 4) << 2); }

__device__ __forceinline__ float redsum64(float v) {
    v += __shfl_xor(v, 32, 64);
    v += __shfl_xor(v, 16, 64);
    v += __shfl_xor(v, 8, 64);
    v += __shfl_xor(v, 4, 64);
    v += __shfl_xor(v, 2, 64);
    v += __shfl_xor(v, 1, 64);
    return v;
}

// quad butterfly via DPP: xor1 = quad_perm 0xB1, xor2 = 0x4E
template <int CTRL>
__device__ __forceinline__ float qp(float v) {
    return __int_as_float(__builtin_amdgcn_update_dpp(0, __float_as_int(v), CTRL, 0xF, 0xF, true));
}
__device__ __forceinline__ float qsum(float v) {
    v += qp<0xB1>(v);
    v += qp<0x4E>(v);
    return v;
}
// octet sum: quad sum + ds_swizzle xor4
__device__ __forceinline__ float osum(float v) {
    v = qsum(v);
    v += __int_as_float(__builtin_amdgcn_ds_swizzle(__float_as_int(v), 0x101F));
    return v;
}

// ---------------------------------------------------------------------------
// dtype detection (flag=1 -> inputs fp32)
// ---------------------------------------------------------------------------
__global__ __launch_bounds__(256) void detect_kernel(const unsigned short* __restrict__ xr,
                                                     int* __restrict__ flag) {
    __shared__ int sh[4];
    int tid = threadIdx.x;
    int cnt = 0;
    for (int i = tid; i < 2048; i += 256) {
        unsigned e = (xr[i] >> 7) & 0xFF;
        if (e >= 110 && e <= 133) cnt++;
    }
    for (int o = 32; o > 0; o >>= 1) cnt += __shfl_xor(cnt, o, 64);
    if ((tid & 63) == 0) sh[tid >> 6] = cnt;
    __syncthreads();
    if (tid == 0) {
        int tot = sh[0] + sh[1] + sh[2] + sh[3];
        *flag = (tot < 1640) ? 1 : 0;
    }
}

// ---------------------------------------------------------------------------
// canonicalize all inputs to fp32 in ws
// ---------------------------------------------------------------------------
struct ConvArgs {
    const void* src[NIN];
    unsigned dstOff[NIN];
    unsigned n[NIN];
    unsigned blockStart[NIN + 1];
};

__global__ __launch_bounds__(256) void convert_kernel(ConvArgs a, float* __restrict__ dst,
                                                      const int* __restrict__ flag) {
    int bid = blockIdx.x;
    int i = 0;
    while (i < NIN - 1 && bid >= (int)a.blockStart[i + 1]) i++;
    unsigned lb = (unsigned)bid - a.blockStart[i];
    unsigned base = lb * 2048 + threadIdx.x;
    unsigned n = a.n[i];
    float* d = dst + a.dstOff[i];
    bool isf32 = (*flag != 0);
    const float* sf = (const float*)a.src[i];
    const unsigned short* su = (const unsigned short*)a.src[i];
#pragma unroll
    for (int e = 0; e < 8; e++) {
        unsigned idx = base + e * 256;
        if (idx < n) d[idx] = isf32 ? sf[idx] : u2f(su[idx]);
    }
}

// ---------------------------------------------------------------------------
// Setup: fuse  M1 = (mi_w[:,128:192] @ mo_w) @ w1 ; bias1 chain
// ---------------------------------------------------------------------------
__global__ __launch_bounds__(256) void fuse_kernel(
    const float* __restrict__ mi_w, const float* __restrict__ mi_b,
    const float* __restrict__ mo_w, const float* __restrict__ mo_b,
    const float* __restrict__ w1, const float* __restrict__ b1,
    float* __restrict__ M1out, float* __restrict__ bias1out) {
    int sl = blockIdx.x;  // 0..5
    __shared__ float T[64][64];
    __shared__ float bT[64];
    const float* Mv = mi_w + sl * 64 * 192;
    const float* Mo = mo_w + sl * 64 * 64;
    for (int idx = threadIdx.x; idx < 64 * 64; idx += 256) {
        int k = idx >> 6, n = idx & 63;
        float acc = 0.f;
        for (int j = 0; j < 64; j++) acc += Mv[k * 192 + 128 + j] * Mo[j * 64 + n];
        T[k][n] = acc;
    }
    for (int n = threadIdx.x; n < 64; n += 256) {
        float acc = mo_b[sl * 64 + n];
        for (int j = 0; j < 64; j++) acc += mi_b[sl * 192 + 128 + j] * Mo[j * 64 + n];
        bT[n] = acc;
    }
    __syncthreads();
    const float* W1 = w1 + sl * 64 * 128;
    for (int idx = threadIdx.x; idx < 64 * 128; idx += 256) {
        int k = idx >> 7, m = idx & 127;
        float acc = 0.f;
        for (int n = 0; n < 64; n++) acc += T[k][n] * W1[n * 128 + m];
        M1out[sl * 64 * 128 + idx] = acc;
    }
    for (int m = threadIdx.x; m < 128; m += 256) {
        float acc = b1[sl * 128 + m];
        for (int n = 0; n < 64; n++) acc += bT[n] * W1[n * 128 + m];
        bias1out[sl * 128 + m] = acc;
    }
}

// ---------------------------------------------------------------------------
// Pass 1: layer 0 over a T-chunk. BC=2, grid = 3*256 = 768 (3 blocks/CU).
// ---------------------------------------------------------------------------
__global__ __launch_bounds__(256, 3) void pass1_kernel(
    const float* __restrict__ x, const float* __restrict__ gw0,
    const float* __restrict__ gb0,
    const float* __restrict__ M1g, const float* __restrict__ bias1g,
    const float* __restrict__ w2g, const float* __restrict__ b2g,
    const float* __restrict__ lag, const float* __restrict__ lab,
    const float* __restrict__ log_, const float* __restrict__ lob,
    const float* __restrict__ rw0, const float* __restrict__ rb0,
    float* __restrict__ gstate,       // [3][512][4][64]
    float* __restrict__ inp_c,        // [3][512][CT][64]
    int t0) {
    const int tid = threadIdx.x;
    const int sIdx = blockIdx.x >> 8;
    const int gbase = (blockIdx.x & 255) * BC;
    const int W = tid >> 6, lane = tid & 63;
    const int q = lane >> 2, ks = lane & 3;
    const int oct = lane >> 3, ks8 = lane & 7;
    const int j = W * 16 + q;
    const int cM = W * 32 + q * 2;
    const int uD = W * 16 + oct * 2;

    const int Li = (sIdx == 0) ? 170 : (sIdx == 1 ? 512 : 256);
    const int st = (sIdx == 0) ? 342 : (sIdx == 1 ? 0 : 256);
    const float sc = (float)Li / 512.0f;

    __shared__ float s_x[2][BC][12];
    __shared__ float s_h[BC][64];
    __shared__ float s_ht[BC][64];
    __shared__ float s_z[BC][160];   // bank-padded (padi)
    __shared__ float s_t2[BC][64];
    __shared__ float s_rw0[768];

    // ---- register weights ----
    const float* gw0s = gw0 + sIdx * IN0 * 256;
    float wx[12], wg[64], wm[32], ww[32];
#pragma unroll
    for (int g = 0; g < 4; g++)
#pragma unroll
        for (int d = 0; d < 3; d++) wx[g * 3 + d] = gw0s[(ks * 3 + d) * 256 + j + 64 * g];
#pragma unroll
    for (int g = 0; g < 4; g++)
#pragma unroll
        for (int kk = 0; kk < 16; kk++) wg[g * 16 + kk] = gw0s[(12 + ks * 16 + kk) * 256 + j + 64 * g];
    const float* M1s = M1g + (sIdx * 2 + 0) * 8192;
#pragma unroll
    for (int cc = 0; cc < 2; cc++)
#pragma unroll
        for (int kk = 0; kk < 16; kk++) wm[cc * 16 + kk] = M1s[(ks * 16 + kk) * 128 + cM + cc];
    const float* w2s = w2g + (sIdx * 2 + 0) * 8192;
#pragma unroll
    for (int cc = 0; cc < 2; cc++)
#pragma unroll
        for (int kk = 0; kk < 16; kk++) ww[cc * 16 + kk] = w2s[(ks8 * 16 + kk) * 64 + uD + cc];

    float h_gb[4];
#pragma unroll
    for (int g = 0; g < 4; g++) h_gb[g] = gb0[sIdx * 256 + j + 64 * g];
    float h_b1[2] = {bias1g[(sIdx * 2 + 0) * 128 + cM], bias1g[(sIdx * 2 + 0) * 128 + cM + 1]};
    float h_b2[2] = {b2g[(sIdx * 2 + 0) * 64 + uD], b2g[(sIdx * 2 + 0) * 64 + uD + 1]};
    // E-phase per-lane constants (unit = lane)
    int ei = (sIdx * 2 + 0) * 64 + lane;
    float eLag = lag[ei], eLab = lab[ei], eLog = log_[ei], eLob = lob[ei];
    float eRb0 = rb0[sIdx * 64 + lane];

    // ---- init ----
    for (int i = tid; i < 768; i += 256) s_rw0[i] = rw0[sIdx * 768 + i];
    for (int i = tid; i < BC * 64; i += 256) {
        int b = i >> 6, jj = i & 63;
        s_h[b][jj] = (t0 == 0) ? 0.f : gstate[((size_t)(sIdx * Bn + gbase + b)) * 256 + jj];
    }
    float cS = 0.f;
    if (t0 != 0 && ks < 2)
        cS = gstate[((size_t)(sIdx * Bn + gbase + ks)) * 256 + 64 + j];
    if (tid < BC * 12) {
        int b = tid / 12, d = tid % 12;
        float srcp = fmaxf((t0 + 0.5f) * sc - 0.5f, 0.f);
        int i0 = (int)floorf(srcp); if (i0 > Li - 1) i0 = Li - 1;
        int i1 = i0 + 1; if (i1 > Li - 1) i1 = Li - 1;
        float w = srcp - (float)i0;
        int gb = gbase + b;
        s_x[0][b][d] = x[(gb * Ln + st + i0) * 12 + d] * (1.0f - w) + x[(gb * Ln + st + i1) * 12 + d] * w;
    }
    __syncthreads();

    for (int tt = 0; tt < CT; tt++) {
        const int sl = tt & 1;
        // ===== A: gates0 + cell =====
        float myF = 0, myI = 0, myG = 0, myO = 0;
#pragma unroll
        for (int b = 0; b < BC; b++) {
            const float4* hp = (const float4*)&s_h[b][ks * 16];
            float4 hv0 = hp[0], hv1 = hp[1], hv2 = hp[2], hv3 = hp[3];
            float x0 = s_x[sl][b][ks * 3], x1 = s_x[sl][b][ks * 3 + 1], x2 = s_x[sl][b][ks * 3 + 2];
            float a0 = (ks == 0) ? h_gb[0] : 0.f;
            float a1 = (ks == 0) ? h_gb[1] : 0.f;
            float a2 = (ks == 0) ? h_gb[2] : 0.f;
            float a3 = (ks == 0) ? h_gb[3] : 0.f;
            a0 = fmaf(wx[0], x0, fmaf(wx[1], x1, fmaf(wx[2], x2, a0)));
            a1 = fmaf(wx[3], x0, fmaf(wx[4], x1, fmaf(wx[5], x2, a1)));
            a2 = fmaf(wx[6], x0, fmaf(wx[7], x1, fmaf(wx[8], x2, a2)));
            a3 = fmaf(wx[9], x0, fmaf(wx[10], x1, fmaf(wx[11], x2, a3)));
            float hk[16] = {hv0.x, hv0.y, hv0.z, hv0.w, hv1.x, hv1.y, hv1.z, hv1.w,
                            hv2.x, hv2.y, hv2.z, hv2.w, hv3.x, hv3.y, hv3.z, hv3.w};
#pragma unroll
            for (int kk = 0; kk < 16; kk++) {
                a0 = fmaf(wg[kk], hk[kk], a0);
                a1 = fmaf(wg[16 + kk], hk[kk], a1);
                a2 = fmaf(wg[32 + kk], hk[kk], a2);
                a3 = fmaf(wg[48 + kk], hk[kk], a3);
            }
            a0 = qsum(a0); a1 = qsum(a1); a2 = qsum(a2); a3 = qsum(a3);
            if (ks == b) { myF = a0; myI = a1; myG = a2; myO = a3; }
        }
        if (ks < 2) {
            float cn = sigm(myF) * cS + sigm(myI) * tanhf(myG);
            cS = cn;
            s_ht[ks][j] = sigm(myO) * tanhf(cn);
        }
        __syncthreads();
        // ===== C: z = gelu(ht @ M1_0 + bias1) =====
        float z0 = 0, z1 = 0;
#pragma unroll
        for (int b = 0; b < BC; b++) {
            const float4* hp = (const float4*)&s_ht[b][ks * 16];
            float4 hv0 = hp[0], hv1 = hp[1], hv2 = hp[2], hv3 = hp[3];
            float a0 = (ks == 0) ? h_b1[0] : 0.f;
            float a1 = (ks == 0) ? h_b1[1] : 0.f;
            float hk[16] = {hv0.x, hv0.y, hv0.z, hv0.w, hv1.x, hv1.y, hv1.z, hv1.w,
                            hv2.x, hv2.y, hv2.z, hv2.w, hv3.x, hv3.y, hv3.z, hv3.w};
#pragma unroll
            for (int kk = 0; kk < 16; kk++) {
                a0 = fmaf(wm[kk], hk[kk], a0);
                a1 = fmaf(wm[16 + kk], hk[kk], a1);
            }
            a0 = qsum(a0); a1 = qsum(a1);
            if (ks == b) { z0 = a0; z1 = a1; }
        }
        if (ks < 2) {
            int zc = padi(cM);
            s_z[ks][zc] = gelu_ex(z0);
            s_z[ks][zc + 1] = gelu_ex(z1);
        }
        __syncthreads();
        // ===== D: t2 = z @ w2_0 + b2 (octet) =====
#pragma unroll
        for (int b = 0; b < BC; b++) {
            const float4* zp = (const float4*)&s_z[b][ks8 * 20];  // padi(ks8*16)
            float4 zv0 = zp[0], zv1 = zp[1], zv2 = zp[2], zv3 = zp[3];
            float a0 = (ks8 == 0) ? h_b2[0] : 0.f;
            float a1 = (ks8 == 0) ? h_b2[1] : 0.f;
            float zk[16] = {zv0.x, zv0.y, zv0.z, zv0.w, zv1.x, zv1.y, zv1.z, zv1.w,
                            zv2.x, zv2.y, zv2.z, zv2.w, zv3.x, zv3.y, zv3.z, zv3.w};
#pragma unroll
            for (int kk = 0; kk < 16; kk++) {
                a0 = fmaf(ww[kk], zk[kk], a0);
                a1 = fmaf(ww[16 + kk], zk[kk], a1);
            }
            a0 = osum(a0); a1 = osum(a1);
            if (ks8 == b) { s_t2[b][uD] = a0; s_t2[b][uD + 1] = a1; }
        }
        __syncthreads();
        // ===== E (waves 0-1: LN chain + inp) ; waves 2-3: stage next x =====
        if (W < 2) {
            const int bb = W;
            float v = s_t2[bb][lane];
            float m = redsum64(v) * (1.0f / 64.0f);
            float var = redsum64(v * v) * (1.0f / 64.0f) - m * m;
            float rs = rsqrtf(fmaxf(var, 0.0f) + 1e-5f);
            float a = (v - m) * rs * eLag + eLab;
            float y = a + s_h[bb][lane];
            float m2 = redsum64(y) * (1.0f / 64.0f);
            float var2 = redsum64(y * y) * (1.0f / 64.0f) - m2 * m2;
            float rs2 = rsqrtf(fmaxf(var2, 0.0f) + 1e-5f);
            float h0n = (y - m2) * rs2 * eLog + eLob;
            s_h[bb][lane] = h0n;
            float p = h0n + eRb0;
#pragma unroll
            for (int d = 0; d < 12; d++)
                p = fmaf(s_x[sl][bb][d], s_rw0[d * 64 + lane], p);
            inp_c[(((size_t)(sIdx * Bn + gbase + bb)) * CT + tt) * 64 + lane] = p;
        } else if (tt + 1 < CT) {
            int idx = tid - 128;
            if (idx < BC * 12) {
                int b = idx / 12, d = idx % 12;
                int t = t0 + tt + 1;
                float srcp = fmaxf((t + 0.5f) * sc - 0.5f, 0.f);
                int i0 = (int)floorf(srcp); if (i0 > Li - 1) i0 = Li - 1;
                int i1 = i0 + 1; if (i1 > Li - 1) i1 = Li - 1;
                float w = srcp - (float)i0;
                int gb = gbase + b;
                s_x[sl ^ 1][b][d] = x[(gb * Ln + st + i0) * 12 + d] * (1.0f - w) + x[(gb * Ln + st + i1) * 12 + d] * w;
            }
        }
        __syncthreads();
    }
    // ---- writeback ----
    for (int i = tid; i < BC * 64; i += 256) {
        int b = i >> 6, jj = i & 63;
        gstate[((size_t)(sIdx * Bn + gbase + b)) * 256 + jj] = s_h[b][jj];
    }
    if (ks < 2)
        gstate[((size_t)(sIdx * Bn + gbase + ks)) * 256 + 64 + j] = cS;
}

// ---------------------------------------------------------------------------
// G1R GEMM: G1R[row][0:256] = inp @ gw1_top + gb1 ; [256:320] = inp @ rw1 + rb1
// grid = 3*86 = 258 (balanced single round), 6 row-tiles of 32 per block.
// ---------------------------------------------------------------------------
__global__ __launch_bounds__(256) void g1r_kernel(
    const float* __restrict__ gw1, const float* __restrict__ gb1,
    const float* __restrict__ rw1, const float* __restrict__ rb1,
    const float* __restrict__ inp_c, float* __restrict__ G1R) {
    const int tid = threadIdx.x;
    const int s = blockIdx.x / 86;
    const int bb = blockIdx.x % 86;
    __shared__ __align__(16) float s_W[64 * 320];
    __shared__ __align__(16) float s_inT[64][36];

    for (int i = tid; i < 64 * 64; i += 256) {
        int k = i >> 6, cq = i & 63;
        ((float4*)&s_W[k * 320])[cq] = ((const float4*)(gw1 + (size_t)s * 128 * 256 + k * 256))[cq];
    }
    for (int i = tid; i < 64 * 16; i += 256) {
        int k = i >> 4, cq = i & 15;
        ((float4*)&s_W[k * 320 + 256])[cq] = ((const float4*)(rw1 + (size_t)s * 64 * 64 + k * 64))[cq];
    }
    const int c4 = tid & 63, rg = tid >> 6;
    float4 bias = *(const float4*)(gb1 + s * 256 + c4 * 4);
    float rbias = rb1[s * 64 + c4];

    const size_t sRow = (size_t)s * Bn * CT;
    for (int tile = 0; tile < 6; tile++) {
        int tIdx = bb * 6 + tile;
        if (tIdx >= 512) break;   // uniform per block
        int r0 = tIdx * 32;
        __syncthreads();
        for (int i = tid; i < 512; i += 256) {
            int r = i >> 4, kq = i & 15;
            float4 v = *(const float4*)(inp_c + (sRow + r0 + r) * 64 + kq * 4);
            s_inT[kq * 4 + 0][r] = v.x;
            s_inT[kq * 4 + 1][r] = v.y;
            s_inT[kq * 4 + 2][r] = v.z;
            s_inT[kq * 4 + 3][r] = v.w;
        }
        __syncthreads();
        float acc[8][4], accR[8];
#pragma unroll
        for (int r = 0; r < 8; r++) {
            acc[r][0] = bias.x; acc[r][1] = bias.y; acc[r][2] = bias.z; acc[r][3] = bias.w;
            accR[r] = rbias;
        }
        for (int k = 0; k < 64; k++) {
            float4 w = *(const float4*)&s_W[k * 320 + c4 * 4];
            float wR = s_W[k * 320 + 256 + c4];
            float4 iA = *(const float4*)&s_inT[k][rg * 8];
            float4 iB = *(const float4*)&s_inT[k][rg * 8 + 4];
            float in8[8] = {iA.x, iA.y, iA.z, iA.w, iB.x, iB.y, iB.z, iB.w};
#pragma unroll
            for (int r = 0; r < 8; r++) {
                acc[r][0] = fmaf(in8[r], w.x, acc[r][0]);
                acc[r][1] = fmaf(in8[r], w.y, acc[r][1]);
                acc[r][2] = fmaf(in8[r], w.z, acc[r][2]);
                acc[r][3] = fmaf(in8[r], w.w, acc[r][3]);
                accR[r] = fmaf(in8[r], wR, accR[r]);
            }
        }
#pragma unroll
        for (int r = 0; r < 8; r++) {
            size_t row = sRow + r0 + rg * 8 + r;
            float4 o; o.x = acc[r][0]; o.y = acc[r][1]; o.z = acc[r][2]; o.w = acc[r][3];
            *(float4*)(G1R + row * 320 + c4 * 4) = o;
            G1R[row * 320 + 256 + c4] = accR[r];
        }
    }
}

// ---------------------------------------------------------------------------
// Pass 2: layer 1 over a T-chunk. BC=2, grid 768, double-buffered G1R staging.
// ---------------------------------------------------------------------------
__global__ __launch_bounds__(256, 3) void pass2_kernel(
    const float* __restrict__ gw1,
    const float* __restrict__ M1g, const float* __restrict__ bias1g,
    const float* __restrict__ w2g, const float* __restrict__ b2g,
    const float* __restrict__ lag, const float* __restrict__ lab,
    const float* __restrict__ log_, const float* __restrict__ lob,
    const float* __restrict__ G1R,
    float* __restrict__ gstate,
    unsigned short* __restrict__ merged_c,
    int t0) {
    const int tid = threadIdx.x;
    const int sIdx = blockIdx.x >> 8;
    const int gbase = (blockIdx.x & 255) * BC;
    const int W = tid >> 6, lane = tid & 63;
    const int q = lane >> 2, ks = lane & 3;
    const int oct = lane >> 3, ks8 = lane & 7;
    const int j = W * 16 + q;
    const int cM = W * 32 + q * 2;
    const int uD = W * 16 + oct * 2;

    __shared__ float s_h[BC][64];
    __shared__ float s_ht[BC][64];
    __shared__ float s_z[BC][160];
    __shared__ float s_t2[BC][64];
    __shared__ __align__(16) float s_G1R[2][BC][400];  // bank-padded, dbuf

    // ---- register weights ----
    const float* gw1s = gw1 + (size_t)sIdx * 128 * 256;
    float wg[64], wm[32], ww[32];
#pragma unroll
    for (int g = 0; g < 4; g++)
#pragma unroll
        for (int kk = 0; kk < 16; kk++) wg[g * 16 + kk] = gw1s[(64 + ks * 16 + kk) * 256 + j + 64 * g];
    const float* M1s = M1g + (sIdx * 2 + 1) * 8192;
#pragma unroll
    for (int cc = 0; cc < 2; cc++)
#pragma unroll
        for (int kk = 0; kk < 16; kk++) wm[cc * 16 + kk] = M1s[(ks * 16 + kk) * 128 + cM + cc];
    const float* w2s = w2g + (sIdx * 2 + 1) * 8192;
#pragma unroll
    for (int cc = 0; cc < 2; cc++)
#pragma unroll
        for (int kk = 0; kk < 16; kk++) ww[cc * 16 + kk] = w2s[(ks8 * 16 + kk) * 64 + uD + cc];

    float h_b1[2] = {bias1g[(sIdx * 2 + 1) * 128 + cM], bias1g[(sIdx * 2 + 1) * 128 + cM + 1]};
    float h_b2[2] = {b2g[(sIdx * 2 + 1) * 64 + uD], b2g[(sIdx * 2 + 1) * 64 + uD + 1]};
    int ei = (sIdx * 2 + 1) * 64 + lane;
    float eLag = lag[ei], eLab = lab[ei], eLog = log_[ei], eLob = lob[ei];

    // ---- init ----
    for (int i = tid; i < BC * 64; i += 256) {
        int b = i >> 6, jj = i & 63;
        s_h[b][jj] = (t0 == 0) ? 0.f : gstate[((size_t)(sIdx * Bn + gbase + b)) * 256 + 128 + jj];
    }
    float cS = 0.f;
    if (t0 != 0 && ks < 2)
        cS = gstate[((size_t)(sIdx * Bn + gbase + ks)) * 256 + 192 + j];
    // stage G1R slot 0 (bank-padded: float4 chunk qd -> padded chunk qd + (qd>>2))
    for (int i = tid; i < BC * 80; i += 256) {
        int b = i / 80, qd = i % 80;
        ((float4*)&s_G1R[0][b][0])[qd + (qd >> 2)] =
            ((const float4*)(G1R + (((size_t)(sIdx * Bn + gbase + b)) * CT + 0) * 320))[qd];
    }
    __syncthreads();

    for (int tt = 0; tt < CT; tt++) {
        const int sl = tt & 1;
        // ===== A: gates1 = G1R + h1 @ gw1_bot; cell =====
        float myF = 0, myI = 0, myG = 0, myO = 0;
#pragma unroll
        for (int b = 0; b < BC; b++) {
            const float4* hp = (const float4*)&s_h[b][ks * 16];
            float4 hv0 = hp[0], hv1 = hp[1], hv2 = hp[2], hv3 = hp[3];
            float g1r = s_G1R[sl][b][padi(ks * 64 + j)];
            float a0 = (ks == 0) ? g1r : 0.f;
            float a1 = (ks == 1) ? g1r : 0.f;
            float a2 = (ks == 2) ? g1r : 0.f;
            float a3 = (ks == 3) ? g1r : 0.f;
            float hk[16] = {hv0.x, hv0.y, hv0.z, hv0.w, hv1.x, hv1.y, hv1.z, hv1.w,
                            hv2.x, hv2.y, hv2.z, hv2.w, hv3.x, hv3.y, hv3.z, hv3.w};
#pragma unroll
            for (int kk = 0; kk < 16; kk++) {
                a0 = fmaf(wg[kk], hk[kk], a0);
                a1 = fmaf(wg[16 + kk], hk[kk], a1);
                a2 = fmaf(wg[32 + kk], hk[kk], a2);
                a3 = fmaf(wg[48 + kk], hk[kk], a3);
            }
            a0 = qsum(a0); a1 = qsum(a1); a2 = qsum(a2); a3 = qsum(a3);
            if (ks == b) { myF = a0; myI = a1; myG = a2; myO = a3; }
        }
        if (ks < 2) {
            float cn = sigm(myF) * cS + sigm(myI) * tanhf(myG);
            cS = cn;
            s_ht[ks][j] = sigm(myO) * tanhf(cn);
        }
        __syncthreads();
        // ===== C: z = gelu(ht @ M1_1 + bias1) =====
        float z0 = 0, z1 = 0;
#pragma unroll
        for (int b = 0; b < BC; b++) {
            const float4* hp = (const float4*)&s_ht[b][ks * 16];
            float4 hv0 = hp[0], hv1 = hp[1], hv2 = hp[2], hv3 = hp[3];
            float a0 = (ks == 0) ? h_b1[0] : 0.f;
            float a1 = (ks == 0) ? h_b1[1] : 0.f;
            float hk[16] = {hv0.x, hv0.y, hv0.z, hv0.w, hv1.x, hv1.y, hv1.z, hv1.w,
                            hv2.x, hv2.y, hv2.z, hv2.w, hv3.x, hv3.y, hv3.z, hv3.w};
#pragma unroll
            for (int kk = 0; kk < 16; kk++) {
                a0 = fmaf(wm[kk], hk[kk], a0);
                a1 = fmaf(wm[16 + kk], hk[kk], a1);
            }
            a0 = qsum(a0); a1 = qsum(a1);
            if (ks == b) { z0 = a0; z1 = a1; }
        }
        if (ks < 2) {
            int zc = padi(cM);
            s_z[ks][zc] = gelu_ex(z0);
            s_z[ks][zc + 1] = gelu_ex(z1);
        }
        __syncthreads();
        // ===== D: t2 = z @ w2_1 + b2 (octet) =====
#pragma unroll
        for (int b = 0; b < BC; b++) {
            const float4* zp = (const float4*)&s_z[b][ks8 * 20];
            float4 zv0 = zp[0], zv1 = zp[1], zv2 = zp[2], zv3 = zp[3];
            float a0 = (ks8 == 0) ? h_b2[0] : 0.f;
            float a1 = (ks8 == 0) ? h_b2[1] : 0.f;
            float zk[16] = {zv0.x, zv0.y, zv0.z, zv0.w, zv1.x, zv1.y, zv1.z, zv1.w,
                            zv2.x, zv2.y, zv2.z, zv2.w, zv3.x, zv3.y, zv3.z, zv3.w};
#pragma unroll
            for (int kk = 0; kk < 16; kk++) {
                a0 = fmaf(ww[kk], zk[kk], a0);
                a1 = fmaf(ww[16 + kk], zk[kk], a1);
            }
            a0 = osum(a0); a1 = osum(a1);
            if (ks8 == b) { s_t2[b][uD] = a0; s_t2[b][uD + 1] = a1; }
        }
        __syncthreads();
        // ===== E (waves 0-1) ; waves 2-3 stage next G1R into other slot =====
        if (W < 2) {
            const int bb = W;
            float v = s_t2[bb][lane];
            float m = redsum64(v) * (1.0f / 64.0f);
            float var = redsum64(v * v) * (1.0f / 64.0f) - m * m;
            float rs = rsqrtf(fmaxf(var, 0.0f) + 1e-5f);
            float a = (v - m) * rs * eLag + eLab;
            float y = a + s_h[bb][lane];
            float m2 = redsum64(y) * (1.0f / 64.0f);
            float var2 = redsum64(y * y) * (1.0f / 64.0f) - m2 * m2;
            float rs2 = rsqrtf(fmaxf(var2, 0.0f) + 1e-5f);
            float h1n = (y - m2) * rs2 * eLog + eLob;
            s_h[bb][lane] = h1n;
            float r = s_G1R[sl][bb][padi(256 + lane)];
            merged_c[(((size_t)(sIdx * Bn + gbase + bb)) * CT + tt) * 64 + lane] = f2u(h1n + r);
        } else if (tt + 1 < CT) {
            int idx = tid - 128;
            for (int i2 = idx; i2 < BC * 80; i2 += 128) {
                int b = i2 / 80, qd = i2 % 80;
                ((float4*)&s_G1R[sl ^ 1][b][0])[qd + (qd >> 2)] =
                    ((const float4*)(G1R + (((size_t)(sIdx * Bn + gbase + b)) * CT + (tt + 1)) * 320))[qd];
            }
        }
        __syncthreads();
    }
    // ---- writeback ----
    for (int i = tid; i < BC * 64; i += 256) {
        int b = i >> 6, jj = i & 63;
        gstate[((size_t)(sIdx * Bn + gbase + b)) * 256 + 128 + jj] = s_h[b][jj];
    }
    if (ks < 2)
        gstate[((size_t)(sIdx * Bn + gbase + ks)) * 256 + 192 + j] = cS;
}

// ---------------------------------------------------------------------------
// Combine (per chunk): softmax over scales, weighted sum -> out
// ---------------------------------------------------------------------------
__global__ __launch_bounds__(256) void combine_kernel(
    const unsigned short* __restrict__ merged_c,
    const float* __restrict__ attn_w,
    void* __restrict__ outv, const int* __restrict__ flag, int t0) {
    int wid = (blockIdx.x << 2) + (threadIdx.x >> 6);
    int lane = threadIdx.x & 63;
    int b = wid / CT, tt = wid % CT;
    float aw = attn_w[lane];
    size_t stride = (size_t)Bn * CT * 64;
    size_t base = (((size_t)b) * CT + tt) * 64 + lane;
    float m0 = u2f(merged_c[base]);
    float m1 = u2f(merged_c[base + stride]);
    float m2 = u2f(merged_c[base + 2 * stride]);
    float e0 = redsum64(m0 * aw);
    float e1 = redsum64(m1 * aw);
    float e2 = redsum64(m2 * aw);
    float mx = fmaxf(e0, fmaxf(e1, e2));
    float x0 = expf(e0 - mx), x1 = expf(e1 - mx), x2 = expf(e2 - mx);
    float inv = 1.0f / (x0 + x1 + x2);
    float val = (x0 * m0 + x1 * m1 + x2 * m2) * inv;
    size_t ob = (((size_t)b) * Ln + t0 + tt) * 64 + lane;
    if (*flag) ((float*)outv)[ob] = val;
    else ((unsigned short*)outv)[ob] = f2u(val);
}

extern "C" void kernel_launch(void* const* d_in, const int* in_sizes, int n_in,
                              void* d_out, int out_size, void* d_ws, size_t ws_size,
                              hipStream_t stream) {
    (void)out_size; (void)ws_size;
    int* flag = (int*)d_ws;
    float* canon = (float*)((char*)d_ws + 16);

    ConvArgs ca;
    size_t tot = 0;
    unsigned nblocks = 0;
    for (int i = 0; i < NIN; i++) {
        ca.src[i] = d_in[i];
        ca.dstOff[i] = (unsigned)tot;
        unsigned n = (unsigned)in_sizes[i];
        ca.n[i] = n;
        ca.blockStart[i] = nblocks;
        nblocks += (n + 2047) / 2048;
        tot += n;
    }
    ca.blockStart[NIN] = nblocks;

    size_t canonBytes = (tot * 4 + 15) & ~(size_t)15;
    char* p = (char*)d_ws + 16 + canonBytes;
    float* M1 = (float*)p;       p += (size_t)3 * 2 * 64 * 128 * 4;
    float* bias1 = (float*)p;    p += (size_t)3 * 2 * 128 * 4;
    float* gstate = (float*)p;   p += (size_t)3 * 512 * 4 * 64 * 4;
    float* inp_c = (float*)p;    p += (size_t)3 * 512 * CT * 64 * 4;
    float* G1R = (float*)p;      p += (size_t)3 * 512 * CT * 320 * 4;
    p = (char*)(((uintptr_t)p + 15) & ~(uintptr_t)15);
    unsigned short* merged_c = (unsigned short*)p;

    const float* x    = canon + ca.dstOff[0];
    const float* gw0  = canon + ca.dstOff[1];
    const float* gb0  = canon + ca.dstOff[2];
    const float* gw1  = canon + ca.dstOff[3];
    const float* gb1  = canon + ca.dstOff[4];
    const float* mi_w = canon + ca.dstOff[5];
    const float* mi_b = canon + ca.dstOff[6];
    const float* mo_w = canon + ca.dstOff[7];
    const float* mo_b = canon + ca.dstOff[8];
    const float* w1   = canon + ca.dstOff[9];
    const float* b1   = canon + ca.dstOff[10];
    const float* w2   = canon + ca.dstOff[11];
    const float* b2   = canon + ca.dstOff[12];
    const float* lag  = canon + ca.dstOff[13];
    const float* lab  = canon + ca.dstOff[14];
    const float* log_ = canon + ca.dstOff[15];
    const float* lob  = canon + ca.dstOff[16];
    const float* rw0  = canon + ca.dstOff[17];
    const float* rb0  = canon + ca.dstOff[18];
    const float* rw1  = canon + ca.dstOff[19];
    const float* rb1  = canon + ca.dstOff[20];
    const float* attn_w = canon + ca.dstOff[21];

    detect_kernel<<<dim3(1), dim3(256), 0, stream>>>((const unsigned short*)d_in[0], flag);
    convert_kernel<<<dim3(nblocks), dim3(256), 0, stream>>>(ca, canon, flag);
    fuse_kernel<<<dim3(6), dim3(256), 0, stream>>>(mi_w, mi_b, mo_w, mo_b, w1, b1, M1, bias1);

    for (int c = 0; c < NCHUNK; c++) {
        int t0 = c * CT;
        pass1_kernel<<<dim3(Sn * (Bn / BC)), dim3(256), 0, stream>>>(
            x, gw0, gb0, M1, bias1, w2, b2, lag, lab, log_, lob,
            rw0, rb0, gstate, inp_c, t0);
        g1r_kernel<<<dim3(3 * 86), dim3(256), 0, stream>>>(
            gw1, gb1, rw1, rb1, inp_c, G1R);
        pass2_kernel<<<dim3(Sn * (Bn / BC)), dim3(256), 0, stream>>>(
            gw1, M1, bias1, w2, b2, lag, lab, log_, lob,
            G1R, gstate, merged_c, t0);
        combine_kernel<<<dim3(Bn * CT / 4), dim3(256), 0, stream>>>(
            merged_c, attn_w, d_out, flag, t0);
    }
}

// Round 7
// 6421.611 us; speedup vs baseline: 1.2280x; 1.2280x over previous
//
#include <hip/hip_runtime.h>
#include <hip/hip_bf16.h>
#include <math.h>

// Problem constants
#define Sn 3
#define Hn 64
#define Dn 12
#define Bn 512
#define Ln 512
#define BC 2            // batch elems per workgroup
#define IN0 76          // D + H
#define NIN 22
#define CT 32           // timesteps per chunk
#define NCHUNK (Ln / CT)

using bf16 = __hip_bfloat16;

__device__ __forceinline__ float u2f(unsigned short x) {
    return __uint_as_float(((unsigned int)x) << 16);
}
__device__ __forceinline__ unsigned short f2u(float f) {
    bf16 h = __float2bfloat16(f);
    unsigned short u;
    __builtin_memcpy(&u, &h, 2);
    return u;
}
__device__ __forceinline__ float sigm(float x) { return 1.0f / (1.0f + expf(-x)); }
__device__ __forceinline__ float gelu_ex(float x) { return 0.5f * x * (1.0f + erff(x * 0.70710678118654752f)); }
// bank-pad: insert 4 floats of pad every 16 (keeps 16-float blocks contiguous/16B-aligned)
__device__ __forceinline__ int padi(int c) { return c + ((c >> 4) << 2); }

__device__ __forceinline__ float redsum64(float v) {
    v += __shfl_xor(v, 32, 64);
    v += __shfl_xor(v, 16, 64);
    v += __shfl_xor(v, 8, 64);
    v += __shfl_xor(v, 4, 64);
    v += __shfl_xor(v, 2, 64);
    v += __shfl_xor(v, 1, 64);
    return v;
}

// quad butterfly via DPP: xor1 = quad_perm 0xB1, xor2 = 0x4E
template <int CTRL>
__device__ __forceinline__ float qp(float v) {
    return __int_as_float(__builtin_amdgcn_update_dpp(0, __float_as_int(v), CTRL, 0xF, 0xF, true));
}
__device__ __forceinline__ float qsum(float v) {
    v += qp<0xB1>(v);
    v += qp<0x4E>(v);
    return v;
}
// octet sum: quad sum + ds_swizzle xor4
__device__ __forceinline__ float osum(float v) {
    v = qsum(v);
    v += __int_as_float(__builtin_amdgcn_ds_swizzle(__float_as_int(v), 0x101F));
    return v;
}

// ---------------------------------------------------------------------------
// dtype detection (flag=1 -> inputs fp32)
// ---------------------------------------------------------------------------
__global__ __launch_bounds__(256) void detect_kernel(const unsigned short* __restrict__ xr,
                                                     int* __restrict__ flag) {
    __shared__ int sh[4];
    int tid = threadIdx.x;
    int cnt = 0;
    for (int i = tid; i < 2048; i += 256) {
        unsigned e = (xr[i] >> 7) & 0xFF;
        if (e >= 110 && e <= 133) cnt++;
    }
    for (int o = 32; o > 0; o >>= 1) cnt += __shfl_xor(cnt, o, 64);
    if ((tid & 63) == 0) sh[tid >> 6] = cnt;
    __syncthreads();
    if (tid == 0) {
        int tot = sh[0] + sh[1] + sh[2] + sh[3];
        *flag = (tot < 1640) ? 1 : 0;
    }
}

// ---------------------------------------------------------------------------
// canonicalize all inputs to fp32 in ws
// ---------------------------------------------------------------------------
struct ConvArgs {
    const void* src[NIN];
    unsigned dstOff[NIN];
    unsigned n[NIN];
    unsigned blockStart[NIN + 1];
};

__global__ __launch_bounds__(256) void convert_kernel(ConvArgs a, float* __restrict__ dst,
                                                      const int* __restrict__ flag) {
    int bid = blockIdx.x;
    int i = 0;
    while (i < NIN - 1 && bid >= (int)a.blockStart[i + 1]) i++;
    unsigned lb = (unsigned)bid - a.blockStart[i];
    unsigned base = lb * 2048 + threadIdx.x;
    unsigned n = a.n[i];
    float* d = dst + a.dstOff[i];
    bool isf32 = (*flag != 0);
    const float* sf = (const float*)a.src[i];
    const unsigned short* su = (const unsigned short*)a.src[i];
#pragma unroll
    for (int e = 0; e < 8; e++) {
        unsigned idx = base + e * 256;
        if (idx < n) d[idx] = isf32 ? sf[idx] : u2f(su[idx]);
    }
}

// ---------------------------------------------------------------------------
// Setup: fuse  M1 = (mi_w[:,128:192] @ mo_w) @ w1 ; bias1 chain
// ---------------------------------------------------------------------------
__global__ __launch_bounds__(256) void fuse_kernel(
    const float* __restrict__ mi_w, const float* __restrict__ mi_b,
    const float* __restrict__ mo_w, const float* __restrict__ mo_b,
    const float* __restrict__ w1, const float* __restrict__ b1,
    float* __restrict__ M1out, float* __restrict__ bias1out) {
    int sl = blockIdx.x;  // 0..5
    __shared__ float T[64][64];
    __shared__ float bT[64];
    const float* Mv = mi_w + sl * 64 * 192;
    const float* Mo = mo_w + sl * 64 * 64;
    for (int idx = threadIdx.x; idx < 64 * 64; idx += 256) {
        int k = idx >> 6, n = idx & 63;
        float acc = 0.f;
        for (int j = 0; j < 64; j++) acc += Mv[k * 192 + 128 + j] * Mo[j * 64 + n];
        T[k][n] = acc;
    }
    for (int n = threadIdx.x; n < 64; n += 256) {
        float acc = mo_b[sl * 64 + n];
        for (int j = 0; j < 64; j++) acc += mi_b[sl * 192 + 128 + j] * Mo[j * 64 + n];
        bT[n] = acc;
    }
    __syncthreads();
    const float* W1 = w1 + sl * 64 * 128;
    for (int idx = threadIdx.x; idx < 64 * 128; idx += 256) {
        int k = idx >> 7, m = idx & 127;
        float acc = 0.f;
        for (int n = 0; n < 64; n++) acc += T[k][n] * W1[n * 128 + m];
        M1out[sl * 64 * 128 + idx] = acc;
    }
    for (int m = threadIdx.x; m < 128; m += 256) {
        float acc = b1[sl * 128 + m];
        for (int n = 0; n < 64; n++) acc += bT[n] * W1[n * 128 + m];
        bias1out[sl * 128 + m] = acc;
    }
}

// ---------------------------------------------------------------------------
// Pass 1: layer 0 over a T-chunk. BC=2, grid = 3*256 = 768.
// __launch_bounds__(256,2): VGPR cap 256 -> weight arrays stay in registers
// (at (256,3) the 170-reg cap spilled ~100 regs/lane -> 70 MB scratch WRITE).
// ---------------------------------------------------------------------------
__global__ __launch_bounds__(256, 2) void pass1_kernel(
    const float* __restrict__ x, const float* __restrict__ gw0,
    const float* __restrict__ gb0,
    const float* __restrict__ M1g, const float* __restrict__ bias1g,
    const float* __restrict__ w2g, const float* __restrict__ b2g,
    const float* __restrict__ lag, const float* __restrict__ lab,
    const float* __restrict__ log_, const float* __restrict__ lob,
    const float* __restrict__ rw0, const float* __restrict__ rb0,
    float* __restrict__ gstate,       // [3][512][4][64]
    float* __restrict__ inp_c,        // [3][512][CT][64]
    int t0) {
    const int tid = threadIdx.x;
    const int sIdx = blockIdx.x >> 8;
    const int gbase = (blockIdx.x & 255) * BC;
    const int W = tid >> 6, lane = tid & 63;
    const int q = lane >> 2, ks = lane & 3;
    const int oct = lane >> 3, ks8 = lane & 7;
    const int j = W * 16 + q;
    const int cM = W * 32 + q * 2;
    const int uD = W * 16 + oct * 2;

    const int Li = (sIdx == 0) ? 170 : (sIdx == 1 ? 512 : 256);
    const int st = (sIdx == 0) ? 342 : (sIdx == 1 ? 0 : 256);
    const float sc = (float)Li / 512.0f;

    __shared__ float s_x[2][BC][12];
    __shared__ float s_h[BC][64];
    __shared__ float s_ht[BC][64];
    __shared__ float s_z[BC][160];   // bank-padded (padi)
    __shared__ float s_t2[BC][64];
    __shared__ float s_rw0[768];

    // ---- register weights ----
    const float* gw0s = gw0 + sIdx * IN0 * 256;
    float wx[12], wg[64], wm[32], ww[32];
#pragma unroll
    for (int g = 0; g < 4; g++)
#pragma unroll
        for (int d = 0; d < 3; d++) wx[g * 3 + d] = gw0s[(ks * 3 + d) * 256 + j + 64 * g];
#pragma unroll
    for (int g = 0; g < 4; g++)
#pragma unroll
        for (int kk = 0; kk < 16; kk++) wg[g * 16 + kk] = gw0s[(12 + ks * 16 + kk) * 256 + j + 64 * g];
    const float* M1s = M1g + (sIdx * 2 + 0) * 8192;
#pragma unroll
    for (int cc = 0; cc < 2; cc++)
#pragma unroll
        for (int kk = 0; kk < 16; kk++) wm[cc * 16 + kk] = M1s[(ks * 16 + kk) * 128 + cM + cc];
    const float* w2s = w2g + (sIdx * 2 + 0) * 8192;
#pragma unroll
    for (int cc = 0; cc < 2; cc++)
#pragma unroll
        for (int kk = 0; kk < 16; kk++) ww[cc * 16 + kk] = w2s[(ks8 * 16 + kk) * 64 + uD + cc];

    float h_gb[4];
#pragma unroll
    for (int g = 0; g < 4; g++) h_gb[g] = gb0[sIdx * 256 + j + 64 * g];
    float h_b1[2] = {bias1g[(sIdx * 2 + 0) * 128 + cM], bias1g[(sIdx * 2 + 0) * 128 + cM + 1]};
    float h_b2[2] = {b2g[(sIdx * 2 + 0) * 64 + uD], b2g[(sIdx * 2 + 0) * 64 + uD + 1]};
    // E-phase per-lane constants (unit = lane)
    int ei = (sIdx * 2 + 0) * 64 + lane;
    float eLag = lag[ei], eLab = lab[ei], eLog = log_[ei], eLob = lob[ei];
    float eRb0 = rb0[sIdx * 64 + lane];

    // ---- init ----
    for (int i = tid; i < 768; i += 256) s_rw0[i] = rw0[sIdx * 768 + i];
    for (int i = tid; i < BC * 64; i += 256) {
        int b = i >> 6, jj = i & 63;
        s_h[b][jj] = (t0 == 0) ? 0.f : gstate[((size_t)(sIdx * Bn + gbase + b)) * 256 + jj];
    }
    float cS = 0.f;
    if (t0 != 0 && ks < 2)
        cS = gstate[((size_t)(sIdx * Bn + gbase + ks)) * 256 + 64 + j];
    if (tid < BC * 12) {
        int b = tid / 12, d = tid % 12;
        float srcp = fmaxf((t0 + 0.5f) * sc - 0.5f, 0.f);
        int i0 = (int)floorf(srcp); if (i0 > Li - 1) i0 = Li - 1;
        int i1 = i0 + 1; if (i1 > Li - 1) i1 = Li - 1;
        float w = srcp - (float)i0;
        int gb = gbase + b;
        s_x[0][b][d] = x[(gb * Ln + st + i0) * 12 + d] * (1.0f - w) + x[(gb * Ln + st + i1) * 12 + d] * w;
    }
    __syncthreads();

    for (int tt = 0; tt < CT; tt++) {
        const int sl = tt & 1;
        // ===== A: gates0 + cell =====
        float myF = 0, myI = 0, myG = 0, myO = 0;
#pragma unroll
        for (int b = 0; b < BC; b++) {
            const float4* hp = (const float4*)&s_h[b][ks * 16];
            float4 hv0 = hp[0], hv1 = hp[1], hv2 = hp[2], hv3 = hp[3];
            float x0 = s_x[sl][b][ks * 3], x1 = s_x[sl][b][ks * 3 + 1], x2 = s_x[sl][b][ks * 3 + 2];
            float a0 = (ks == 0) ? h_gb[0] : 0.f;
            float a1 = (ks == 0) ? h_gb[1] : 0.f;
            float a2 = (ks == 0) ? h_gb[2] : 0.f;
            float a3 = (ks == 0) ? h_gb[3] : 0.f;
            a0 = fmaf(wx[0], x0, fmaf(wx[1], x1, fmaf(wx[2], x2, a0)));
            a1 = fmaf(wx[3], x0, fmaf(wx[4], x1, fmaf(wx[5], x2, a1)));
            a2 = fmaf(wx[6], x0, fmaf(wx[7], x1, fmaf(wx[8], x2, a2)));
            a3 = fmaf(wx[9], x0, fmaf(wx[10], x1, fmaf(wx[11], x2, a3)));
            float hk[16] = {hv0.x, hv0.y, hv0.z, hv0.w, hv1.x, hv1.y, hv1.z, hv1.w,
                            hv2.x, hv2.y, hv2.z, hv2.w, hv3.x, hv3.y, hv3.z, hv3.w};
#pragma unroll
            for (int kk = 0; kk < 16; kk++) {
                a0 = fmaf(wg[kk], hk[kk], a0);
                a1 = fmaf(wg[16 + kk], hk[kk], a1);
                a2 = fmaf(wg[32 + kk], hk[kk], a2);
                a3 = fmaf(wg[48 + kk], hk[kk], a3);
            }
            a0 = qsum(a0); a1 = qsum(a1); a2 = qsum(a2); a3 = qsum(a3);
            if (ks == b) { myF = a0; myI = a1; myG = a2; myO = a3; }
        }
        if (ks < 2) {
            float cn = sigm(myF) * cS + sigm(myI) * tanhf(myG);
            cS = cn;
            s_ht[ks][j] = sigm(myO) * tanhf(cn);
        }
        __syncthreads();
        // ===== C: z = gelu(ht @ M1_0 + bias1) =====
        float z0 = 0, z1 = 0;
#pragma unroll
        for (int b = 0; b < BC; b++) {
            const float4* hp = (const float4*)&s_ht[b][ks * 16];
            float4 hv0 = hp[0], hv1 = hp[1], hv2 = hp[2], hv3 = hp[3];
            float a0 = (ks == 0) ? h_b1[0] : 0.f;
            float a1 = (ks == 0) ? h_b1[1] : 0.f;
            float hk[16] = {hv0.x, hv0.y, hv0.z, hv0.w, hv1.x, hv1.y, hv1.z, hv1.w,
                            hv2.x, hv2.y, hv2.z, hv2.w, hv3.x, hv3.y, hv3.z, hv3.w};
#pragma unroll
            for (int kk = 0; kk < 16; kk++) {
                a0 = fmaf(wm[kk], hk[kk], a0);
                a1 = fmaf(wm[16 + kk], hk[kk], a1);
            }
            a0 = qsum(a0); a1 = qsum(a1);
            if (ks == b) { z0 = a0; z1 = a1; }
        }
        if (ks < 2) {
            int zc = padi(cM);
            s_z[ks][zc] = gelu_ex(z0);
            s_z[ks][zc + 1] = gelu_ex(z1);
        }
        __syncthreads();
        // ===== D: t2 = z @ w2_0 + b2 (octet) =====
#pragma unroll
        for (int b = 0; b < BC; b++) {
            const float4* zp = (const float4*)&s_z[b][ks8 * 20];  // padi(ks8*16)
            float4 zv0 = zp[0], zv1 = zp[1], zv2 = zp[2], zv3 = zp[3];
            float a0 = (ks8 == 0) ? h_b2[0] : 0.f;
            float a1 = (ks8 == 0) ? h_b2[1] : 0.f;
            float zk[16] = {zv0.x, zv0.y, zv0.z, zv0.w, zv1.x, zv1.y, zv1.z, zv1.w,
                            zv2.x, zv2.y, zv2.z, zv2.w, zv3.x, zv3.y, zv3.z, zv3.w};
#pragma unroll
            for (int kk = 0; kk < 16; kk++) {
                a0 = fmaf(ww[kk], zk[kk], a0);
                a1 = fmaf(ww[16 + kk], zk[kk], a1);
            }
            a0 = osum(a0); a1 = osum(a1);
            if (ks8 == b) { s_t2[b][uD] = a0; s_t2[b][uD + 1] = a1; }
        }
        __syncthreads();
        // ===== E (waves 0-1: LN chain + inp) ; waves 2-3: stage next x =====
        if (W < 2) {
            const int bb = W;
            float v = s_t2[bb][lane];
            float m = redsum64(v) * (1.0f / 64.0f);
            float var = redsum64(v * v) * (1.0f / 64.0f) - m * m;
            float rs = rsqrtf(fmaxf(var, 0.0f) + 1e-5f);
            float a = (v - m) * rs * eLag + eLab;
            float y = a + s_h[bb][lane];
            float m2 = redsum64(y) * (1.0f / 64.0f);
            float var2 = redsum64(y * y) * (1.0f / 64.0f) - m2 * m2;
            float rs2 = rsqrtf(fmaxf(var2, 0.0f) + 1e-5f);
            float h0n = (y - m2) * rs2 * eLog + eLob;
            s_h[bb][lane] = h0n;
            float p = h0n + eRb0;
#pragma unroll
            for (int d = 0; d < 12; d++)
                p = fmaf(s_x[sl][bb][d], s_rw0[d * 64 + lane], p);
            inp_c[(((size_t)(sIdx * Bn + gbase + bb)) * CT + tt) * 64 + lane] = p;
        } else if (tt + 1 < CT) {
            int idx = tid - 128;
            if (idx < BC * 12) {
                int b = idx / 12, d = idx % 12;
                int t = t0 + tt + 1;
                float srcp = fmaxf((t + 0.5f) * sc - 0.5f, 0.f);
                int i0 = (int)floorf(srcp); if (i0 > Li - 1) i0 = Li - 1;
                int i1 = i0 + 1; if (i1 > Li - 1) i1 = Li - 1;
                float w = srcp - (float)i0;
                int gb = gbase + b;
                s_x[sl ^ 1][b][d] = x[(gb * Ln + st + i0) * 12 + d] * (1.0f - w) + x[(gb * Ln + st + i1) * 12 + d] * w;
            }
        }
        __syncthreads();
    }
    // ---- writeback ----
    for (int i = tid; i < BC * 64; i += 256) {
        int b = i >> 6, jj = i & 63;
        gstate[((size_t)(sIdx * Bn + gbase + b)) * 256 + jj] = s_h[b][jj];
    }
    if (ks < 2)
        gstate[((size_t)(sIdx * Bn + gbase + ks)) * 256 + 64 + j] = cS;
}

// ---------------------------------------------------------------------------
// G1R GEMM: G1R[row][0:256] = inp @ gw1_top + gb1 ; [256:320] = inp @ rw1 + rb1
// ---------------------------------------------------------------------------
__global__ __launch_bounds__(256) void g1r_kernel(
    const float* __restrict__ gw1, const float* __restrict__ gb1,
    const float* __restrict__ rw1, const float* __restrict__ rb1,
    const float* __restrict__ inp_c, float* __restrict__ G1R) {
    const int tid = threadIdx.x;
    const int s = blockIdx.x / 86;
    const int bb = blockIdx.x % 86;
    __shared__ __align__(16) float s_W[64 * 320];
    __shared__ __align__(16) float s_inT[64][36];

    for (int i = tid; i < 64 * 64; i += 256) {
        int k = i >> 6, cq = i & 63;
        ((float4*)&s_W[k * 320])[cq] = ((const float4*)(gw1 + (size_t)s * 128 * 256 + k * 256))[cq];
    }
    for (int i = tid; i < 64 * 16; i += 256) {
        int k = i >> 4, cq = i & 15;
        ((float4*)&s_W[k * 320 + 256])[cq] = ((const float4*)(rw1 + (size_t)s * 64 * 64 + k * 64))[cq];
    }
    const int c4 = tid & 63, rg = tid >> 6;
    float4 bias = *(const float4*)(gb1 + s * 256 + c4 * 4);
    float rbias = rb1[s * 64 + c4];

    const size_t sRow = (size_t)s * Bn * CT;
    for (int tile = 0; tile < 6; tile++) {
        int tIdx = bb * 6 + tile;
        if (tIdx >= 512) break;   // uniform per block
        int r0 = tIdx * 32;
        __syncthreads();
        for (int i = tid; i < 512; i += 256) {
            int r = i >> 4, kq = i & 15;
            float4 v = *(const float4*)(inp_c + (sRow + r0 + r) * 64 + kq * 4);
            s_inT[kq * 4 + 0][r] = v.x;
            s_inT[kq * 4 + 1][r] = v.y;
            s_inT[kq * 4 + 2][r] = v.z;
            s_inT[kq * 4 + 3][r] = v.w;
        }
        __syncthreads();
        float acc[8][4], accR[8];
#pragma unroll
        for (int r = 0; r < 8; r++) {
            acc[r][0] = bias.x; acc[r][1] = bias.y; acc[r][2] = bias.z; acc[r][3] = bias.w;
            accR[r] = rbias;
        }
        for (int k = 0; k < 64; k++) {
            float4 w = *(const float4*)&s_W[k * 320 + c4 * 4];
            float wR = s_W[k * 320 + 256 + c4];
            float4 iA = *(const float4*)&s_inT[k][rg * 8];
            float4 iB = *(const float4*)&s_inT[k][rg * 8 + 4];
            float in8[8] = {iA.x, iA.y, iA.z, iA.w, iB.x, iB.y, iB.z, iB.w};
#pragma unroll
            for (int r = 0; r < 8; r++) {
                acc[r][0] = fmaf(in8[r], w.x, acc[r][0]);
                acc[r][1] = fmaf(in8[r], w.y, acc[r][1]);
                acc[r][2] = fmaf(in8[r], w.z, acc[r][2]);
                acc[r][3] = fmaf(in8[r], w.w, acc[r][3]);
                accR[r] = fmaf(in8[r], wR, accR[r]);
            }
        }
#pragma unroll
        for (int r = 0; r < 8; r++) {
            size_t row = sRow + r0 + rg * 8 + r;
            float4 o; o.x = acc[r][0]; o.y = acc[r][1]; o.z = acc[r][2]; o.w = acc[r][3];
            *(float4*)(G1R + row * 320 + c4 * 4) = o;
            G1R[row * 320 + 256 + c4] = accR[r];
        }
    }
}

// ---------------------------------------------------------------------------
// Pass 2: layer 1 over a T-chunk. BC=2, grid 768, launch_bounds(256,2).
// ---------------------------------------------------------------------------
__global__ __launch_bounds__(256, 2) void pass2_kernel(
    const float* __restrict__ gw1,
    const float* __restrict__ M1g, const float* __restrict__ bias1g,
    const float* __restrict__ w2g, const float* __restrict__ b2g,
    const float* __restrict__ lag, const float* __restrict__ lab,
    const float* __restrict__ log_, const float* __restrict__ lob,
    const float* __restrict__ G1R,
    float* __restrict__ gstate,
    unsigned short* __restrict__ merged_c,
    int t0) {
    const int tid = threadIdx.x;
    const int sIdx = blockIdx.x >> 8;
    const int gbase = (blockIdx.x & 255) * BC;
    const int W = tid >> 6, lane = tid & 63;
    const int q = lane >> 2, ks = lane & 3;
    const int oct = lane >> 3, ks8 = lane & 7;
    const int j = W * 16 + q;
    const int cM = W * 32 + q * 2;
    const int uD = W * 16 + oct * 2;

    __shared__ float s_h[BC][64];
    __shared__ float s_ht[BC][64];
    __shared__ float s_z[BC][160];
    __shared__ float s_t2[BC][64];
    __shared__ __align__(16) float s_G1R[2][BC][400];  // bank-padded, dbuf

    // ---- register weights ----
    const float* gw1s = gw1 + (size_t)sIdx * 128 * 256;
    float wg[64], wm[32], ww[32];
#pragma unroll
    for (int g = 0; g < 4; g++)
#pragma unroll
        for (int kk = 0; kk < 16; kk++) wg[g * 16 + kk] = gw1s[(64 + ks * 16 + kk) * 256 + j + 64 * g];
    const float* M1s = M1g + (sIdx * 2 + 1) * 8192;
#pragma unroll
    for (int cc = 0; cc < 2; cc++)
#pragma unroll
        for (int kk = 0; kk < 16; kk++) wm[cc * 16 + kk] = M1s[(ks * 16 + kk) * 128 + cM + cc];
    const float* w2s = w2g + (sIdx * 2 + 1) * 8192;
#pragma unroll
    for (int cc = 0; cc < 2; cc++)
#pragma unroll
        for (int kk = 0; kk < 16; kk++) ww[cc * 16 + kk] = w2s[(ks8 * 16 + kk) * 64 + uD + cc];

    float h_b1[2] = {bias1g[(sIdx * 2 + 1) * 128 + cM], bias1g[(sIdx * 2 + 1) * 128 + cM + 1]};
    float h_b2[2] = {b2g[(sIdx * 2 + 1) * 64 + uD], b2g[(sIdx * 2 + 1) * 64 + uD + 1]};
    int ei = (sIdx * 2 + 1) * 64 + lane;
    float eLag = lag[ei], eLab = lab[ei], eLog = log_[ei], eLob = lob[ei];

    // ---- init ----
    for (int i = tid; i < BC * 64; i += 256) {
        int b = i >> 6, jj = i & 63;
        s_h[b][jj] = (t0 == 0) ? 0.f : gstate[((size_t)(sIdx * Bn + gbase + b)) * 256 + 128 + jj];
    }
    float cS = 0.f;
    if (t0 != 0 && ks < 2)
        cS = gstate[((size_t)(sIdx * Bn + gbase + ks)) * 256 + 192 + j];
    // stage G1R slot 0 (bank-padded: float4 chunk qd -> padded chunk qd + (qd>>2))
    for (int i = tid; i < BC * 80; i += 256) {
        int b = i / 80, qd = i % 80;
        ((float4*)&s_G1R[0][b][0])[qd + (qd >> 2)] =
            ((const float4*)(G1R + (((size_t)(sIdx * Bn + gbase + b)) * CT + 0) * 320))[qd];
    }
    __syncthreads();

    for (int tt = 0; tt < CT; tt++) {
        const int sl = tt & 1;
        // ===== A: gates1 = G1R + h1 @ gw1_bot; cell =====
        float myF = 0, myI = 0, myG = 0, myO = 0;
#pragma unroll
        for (int b = 0; b < BC; b++) {
            const float4* hp = (const float4*)&s_h[b][ks * 16];
            float4 hv0 = hp[0], hv1 = hp[1], hv2 = hp[2], hv3 = hp[3];
            float g1r = s_G1R[sl][b][padi(ks * 64 + j)];
            float a0 = (ks == 0) ? g1r : 0.f;
            float a1 = (ks == 1) ? g1r : 0.f;
            float a2 = (ks == 2) ? g1r : 0.f;
            float a3 = (ks == 3) ? g1r : 0.f;
            float hk[16] = {hv0.x, hv0.y, hv0.z, hv0.w, hv1.x, hv1.y, hv1.z, hv1.w,
                            hv2.x, hv2.y, hv2.z, hv2.w, hv3.x, hv3.y, hv3.z, hv3.w};
#pragma unroll
            for (int kk = 0; kk < 16; kk++) {
                a0 = fmaf(wg[kk], hk[kk], a0);
                a1 = fmaf(wg[16 + kk], hk[kk], a1);
                a2 = fmaf(wg[32 + kk], hk[kk], a2);
                a3 = fmaf(wg[48 + kk], hk[kk], a3);
            }
            a0 = qsum(a0); a1 = qsum(a1); a2 = qsum(a2); a3 = qsum(a3);
            if (ks == b) { myF = a0; myI = a1; myG = a2; myO = a3; }
        }
        if (ks < 2) {
            float cn = sigm(myF) * cS + sigm(myI) * tanhf(myG);
            cS = cn;
            s_ht[ks][j] = sigm(myO) * tanhf(cn);
        }
        __syncthreads();
        // ===== C: z = gelu(ht @ M1_1 + bias1) =====
        float z0 = 0, z1 = 0;
#pragma unroll
        for (int b = 0; b < BC; b++) {
            const float4* hp = (const float4*)&s_ht[b][ks * 16];
            float4 hv0 = hp[0], hv1 = hp[1], hv2 = hp[2], hv3 = hp[3];
            float a0 = (ks == 0) ? h_b1[0] : 0.f;
            float a1 = (ks == 0) ? h_b1[1] : 0.f;
            float hk[16] = {hv0.x, hv0.y, hv0.z, hv0.w, hv1.x, hv1.y, hv1.z, hv1.w,
                            hv2.x, hv2.y, hv2.z, hv2.w, hv3.x, hv3.y, hv3.z, hv3.w};
#pragma unroll
            for (int kk = 0; kk < 16; kk++) {
                a0 = fmaf(wm[kk], hk[kk], a0);
                a1 = fmaf(wm[16 + kk], hk[kk], a1);
            }
            a0 = qsum(a0); a1 = qsum(a1);
            if (ks == b) { z0 = a0; z1 = a1; }
        }
        if (ks < 2) {
            int zc = padi(cM);
            s_z[ks][zc] = gelu_ex(z0);
            s_z[ks][zc + 1] = gelu_ex(z1);
        }
        __syncthreads();
        // ===== D: t2 = z @ w2_1 + b2 (octet) =====
#pragma unroll
        for (int b = 0; b < BC; b++) {
            const float4* zp = (const float4*)&s_z[b][ks8 * 20];
            float4 zv0 = zp[0], zv1 = zp[1], zv2 = zp[2], zv3 = zp[3];
            float a0 = (ks8 == 0) ? h_b2[0] : 0.f;
            float a1 = (ks8 == 0) ? h_b2[1] : 0.f;
            float zk[16] = {zv0.x, zv0.y, zv0.z, zv0.w, zv1.x, zv1.y, zv1.z, zv1.w,
                            zv2.x, zv2.y, zv2.z, zv2.w, zv3.x, zv3.y, zv3.z, zv3.w};
#pragma unroll
            for (int kk = 0; kk < 16; kk++) {
                a0 = fmaf(ww[kk], zk[kk], a0);
                a1 = fmaf(ww[16 + kk], zk[kk], a1);
            }
            a0 = osum(a0); a1 = osum(a1);
            if (ks8 == b) { s_t2[b][uD] = a0; s_t2[b][uD + 1] = a1; }
        }
        __syncthreads();
        // ===== E (waves 0-1) ; waves 2-3 stage next G1R into other slot =====
        if (W < 2) {
            const int bb = W;
            float v = s_t2[bb][lane];
            float m = redsum64(v) * (1.0f / 64.0f);
            float var = redsum64(v * v) * (1.0f / 64.0f) - m * m;
            float rs = rsqrtf(fmaxf(var, 0.0f) + 1e-5f);
            float a = (v - m) * rs * eLag + eLab;
            float y = a + s_h[bb][lane];
            float m2 = redsum64(y) * (1.0f / 64.0f);
            float var2 = redsum64(y * y) * (1.0f / 64.0f) - m2 * m2;
            float rs2 = rsqrtf(fmaxf(var2, 0.0f) + 1e-5f);
            float h1n = (y - m2) * rs2 * eLog + eLob;
            s_h[bb][lane] = h1n;
            float r = s_G1R[sl][bb][padi(256 + lane)];
            merged_c[(((size_t)(sIdx * Bn + gbase + bb)) * CT + tt) * 64 + lane] = f2u(h1n + r);
        } else if (tt + 1 < CT) {
            int idx = tid - 128;
            for (int i2 = idx; i2 < BC * 80; i2 += 128) {
                int b = i2 / 80, qd = i2 % 80;
                ((float4*)&s_G1R[sl ^ 1][b][0])[qd + (qd >> 2)] =
                    ((const float4*)(G1R + (((size_t)(sIdx * Bn + gbase + b)) * CT + (tt + 1)) * 320))[qd];
            }
        }
        __syncthreads();
    }
    // ---- writeback ----
    for (int i = tid; i < BC * 64; i += 256) {
        int b = i >> 6, jj = i & 63;
        gstate[((size_t)(sIdx * Bn + gbase + b)) * 256 + 128 + jj] = s_h[b][jj];
    }
    if (ks < 2)
        gstate[((size_t)(sIdx * Bn + gbase + ks)) * 256 + 192 + j] = cS;
}

// ---------------------------------------------------------------------------
// Combine (per chunk): softmax over scales, weighted sum -> out
// ---------------------------------------------------------------------------
__global__ __launch_bounds__(256) void combine_kernel(
    const unsigned short* __restrict__ merged_c,
    const float* __restrict__ attn_w,
    void* __restrict__ outv, const int* __restrict__ flag, int t0) {
    int wid = (blockIdx.x << 2) + (threadIdx.x >> 6);
    int lane = threadIdx.x & 63;
    int b = wid / CT, tt = wid % CT;
    float aw = attn_w[lane];
    size_t stride = (size_t)Bn * CT * 64;
    size_t base = (((size_t)b) * CT + tt) * 64 + lane;
    float m0 = u2f(merged_c[base]);
    float m1 = u2f(merged_c[base + stride]);
    float m2 = u2f(merged_c[base + 2 * stride]);
    float e0 = redsum64(m0 * aw);
    float e1 = redsum64(m1 * aw);
    float e2 = redsum64(m2 * aw);
    float mx = fmaxf(e0, fmaxf(e1, e2));
    float x0 = expf(e0 - mx), x1 = expf(e1 - mx), x2 = expf(e2 - mx);
    float inv = 1.0f / (x0 + x1 + x2);
    float val = (x0 * m0 + x1 * m1 + x2 * m2) * inv;
    size_t ob = (((size_t)b) * Ln + t0 + tt) * 64 + lane;
    if (*flag) ((float*)outv)[ob] = val;
    else ((unsigned short*)outv)[ob] = f2u(val);
}

extern "C" void kernel_launch(void* const* d_in, const int* in_sizes, int n_in,
                              void* d_out, int out_size, void* d_ws, size_t ws_size,
                              hipStream_t stream) {
    (void)out_size; (void)ws_size;
    int* flag = (int*)d_ws;
    float* canon = (float*)((char*)d_ws + 16);

    ConvArgs ca;
    size_t tot = 0;
    unsigned nblocks = 0;
    for (int i = 0; i < NIN; i++) {
        ca.src[i] = d_in[i];
        ca.dstOff[i] = (unsigned)tot;
        unsigned n = (unsigned)in_sizes[i];
        ca.n[i] = n;
        ca.blockStart[i] = nblocks;
        nblocks += (n + 2047) / 2048;
        tot += n;
    }
    ca.blockStart[NIN] = nblocks;

    size_t canonBytes = (tot * 4 + 15) & ~(size_t)15;
    char* p = (char*)d_ws + 16 + canonBytes;
    float* M1 = (float*)p;       p += (size_t)3 * 2 * 64 * 128 * 4;
    float* bias1 = (float*)p;    p += (size_t)3 * 2 * 128 * 4;
    float* gstate = (float*)p;   p += (size_t)3 * 512 * 4 * 64 * 4;
    float* inp_c = (float*)p;    p += (size_t)3 * 512 * CT * 64 * 4;
    float* G1R = (float*)p;      p += (size_t)3 * 512 * CT * 320 * 4;
    p = (char*)(((uintptr_t)p + 15) & ~(uintptr_t)15);
    unsigned short* merged_c = (unsigned short*)p;

    const float* x    = canon + ca.dstOff[0];
    const float* gw0  = canon + ca.dstOff[1];
    const float* gb0  = canon + ca.dstOff[2];
    const float* gw1  = canon + ca.dstOff[3];
    const float* gb1  = canon + ca.dstOff[4];
    const float* mi_w = canon + ca.dstOff[5];
    const float* mi_b = canon + ca.dstOff[6];
    const float* mo_w = canon + ca.dstOff[7];
    const float* mo_b = canon + ca.dstOff[8];
    const float* w1   = canon + ca.dstOff[9];
    const float* b1   = canon + ca.dstOff[10];
    const float* w2   = canon + ca.dstOff[11];
    const float* b2   = canon + ca.dstOff[12];
    const float* lag  = canon + ca.dstOff[13];
    const float* lab  = canon + ca.dstOff[14];
    const float* log_ = canon + ca.dstOff[15];
    const float* lob  = canon + ca.dstOff[16];
    const float* rw0  = canon + ca.dstOff[17];
    const float* rb0  = canon + ca.dstOff[18];
    const float* rw1  = canon + ca.dstOff[19];
    const float* rb1  = canon + ca.dstOff[20];
    const float* attn_w = canon + ca.dstOff[21];

    detect_kernel<<<dim3(1), dim3(256), 0, stream>>>((const unsigned short*)d_in[0], flag);
    convert_kernel<<<dim3(nblocks), dim3(256), 0, stream>>>(ca, canon, flag);
    fuse_kernel<<<dim3(6), dim3(256), 0, stream>>>(mi_w, mi_b, mo_w, mo_b, w1, b1, M1, bias1);

    for (int c = 0; c < NCHUNK; c++) {
        int t0 = c * CT;
        pass1_kernel<<<dim3(Sn * (Bn / BC)), dim3(256), 0, stream>>>(
            x, gw0, gb0, M1, bias1, w2, b2, lag, lab, log_, lob,
            rw0, rb0, gstate, inp_c, t0);
        g1r_kernel<<<dim3(3 * 86), dim3(256), 0, stream>>>(
            gw1, gb1, rw1, rb1, inp_c, G1R);
        pass2_kernel<<<dim3(Sn * (Bn / BC)), dim3(256), 0, stream>>>(
            gw1, M1, bias1, w2, b2, lag, lab, log_, lob,
            G1R, gstate, merged_c, t0);
        combine_kernel<<<dim3(Bn * CT / 4), dim3(256), 0, stream>>>(
            merged_c, attn_w, d_out, flag, t0);
    }
}

// Round 8
// 5745.951 us; speedup vs baseline: 1.3724x; 1.1176x over previous
//
#include <hip/hip_runtime.h>
#include <hip/hip_bf16.h>
#include <math.h>

// Problem constants
#define Sn 3
#define Hn 64
#define Dn 12
#define Bn 512
#define Ln 512
#define BC 4            // batch elems per workgroup (one per wave for E-phase)
#define IN0 76          // D + H
#define NIN 22
#define CT 32           // timesteps per chunk
#define NCHUNK (Ln / CT)

using bf16 = __hip_bfloat16;
typedef __attribute__((ext_vector_type(2))) float f2;

__device__ __forceinline__ f2 fma2(f2 a, f2 b, f2 c) {
#if __has_builtin(__builtin_elementwise_fma)
    return __builtin_elementwise_fma(a, b, c);
#else
    f2 r; r.x = fmaf(a.x, b.x, c.x); r.y = fmaf(a.y, b.y, c.y); return r;
#endif
}

__device__ __forceinline__ float u2f(unsigned short x) {
    return __uint_as_float(((unsigned int)x) << 16);
}
__device__ __forceinline__ unsigned short f2u(float f) {
    bf16 h = __float2bfloat16(f);
    unsigned short u;
    __builtin_memcpy(&u, &h, 2);
    return u;
}
__device__ __forceinline__ float sigm(float x) { return 1.0f / (1.0f + expf(-x)); }
__device__ __forceinline__ float gelu_ex(float x) { return 0.5f * x * (1.0f + erff(x * 0.70710678118654752f)); }
// bank-pad: insert 4 floats of pad every 16
__device__ __forceinline__ int padi(int c) { return c + ((c >> 4) << 2); }

__device__ __forceinline__ float redsum64(float v) {
    v += __shfl_xor(v, 32, 64);
    v += __shfl_xor(v, 16, 64);
    v += __shfl_xor(v, 8, 64);
    v += __shfl_xor(v, 4, 64);
    v += __shfl_xor(v, 2, 64);
    v += __shfl_xor(v, 1, 64);
    return v;
}

// quad butterfly via DPP: xor1 = quad_perm 0xB1, xor2 = 0x4E
template <int CTRL>
__device__ __forceinline__ float qp(float v) {
    return __int_as_float(__builtin_amdgcn_update_dpp(0, __float_as_int(v), CTRL, 0xF, 0xF, true));
}
__device__ __forceinline__ float qsum(float v) {
    v += qp<0xB1>(v);
    v += qp<0x4E>(v);
    return v;
}
// octet sum: quad sum + ds_swizzle xor4
__device__ __forceinline__ float osum(float v) {
    v = qsum(v);
    v += __int_as_float(__builtin_amdgcn_ds_swizzle(__float_as_int(v), 0x101F));
    return v;
}

// ---------------------------------------------------------------------------
// dtype detection (flag=1 -> inputs fp32)
// ---------------------------------------------------------------------------
__global__ __launch_bounds__(256) void detect_kernel(const unsigned short* __restrict__ xr,
                                                     int* __restrict__ flag) {
    __shared__ int sh[4];
    int tid = threadIdx.x;
    int cnt = 0;
    for (int i = tid; i < 2048; i += 256) {
        unsigned e = (xr[i] >> 7) & 0xFF;
        if (e >= 110 && e <= 133) cnt++;
    }
    for (int o = 32; o > 0; o >>= 1) cnt += __shfl_xor(cnt, o, 64);
    if ((tid & 63) == 0) sh[tid >> 6] = cnt;
    __syncthreads();
    if (tid == 0) {
        int tot = sh[0] + sh[1] + sh[2] + sh[3];
        *flag = (tot < 1640) ? 1 : 0;
    }
}

// ---------------------------------------------------------------------------
// canonicalize all inputs to fp32 in ws
// ---------------------------------------------------------------------------
struct ConvArgs {
    const void* src[NIN];
    unsigned dstOff[NIN];
    unsigned n[NIN];
    unsigned blockStart[NIN + 1];
};

__global__ __launch_bounds__(256) void convert_kernel(ConvArgs a, float* __restrict__ dst,
                                                      const int* __restrict__ flag) {
    int bid = blockIdx.x;
    int i = 0;
    while (i < NIN - 1 && bid >= (int)a.blockStart[i + 1]) i++;
    unsigned lb = (unsigned)bid - a.blockStart[i];
    unsigned base = lb * 2048 + threadIdx.x;
    unsigned n = a.n[i];
    float* d = dst + a.dstOff[i];
    bool isf32 = (*flag != 0);
    const float* sf = (const float*)a.src[i];
    const unsigned short* su = (const unsigned short*)a.src[i];
#pragma unroll
    for (int e = 0; e < 8; e++) {
        unsigned idx = base + e * 256;
        if (idx < n) d[idx] = isf32 ? sf[idx] : u2f(su[idx]);
    }
}

// ---------------------------------------------------------------------------
// Setup: fuse  M1 = (mi_w[:,128:192] @ mo_w) @ w1 ; bias1 chain
// ---------------------------------------------------------------------------
__global__ __launch_bounds__(256) void fuse_kernel(
    const float* __restrict__ mi_w, const float* __restrict__ mi_b,
    const float* __restrict__ mo_w, const float* __restrict__ mo_b,
    const float* __restrict__ w1, const float* __restrict__ b1,
    float* __restrict__ M1out, float* __restrict__ bias1out) {
    int sl = blockIdx.x;  // 0..5
    __shared__ float T[64][64];
    __shared__ float bT[64];
    const float* Mv = mi_w + sl * 64 * 192;
    const float* Mo = mo_w + sl * 64 * 64;
    for (int idx = threadIdx.x; idx < 64 * 64; idx += 256) {
        int k = idx >> 6, n = idx & 63;
        float acc = 0.f;
        for (int j = 0; j < 64; j++) acc += Mv[k * 192 + 128 + j] * Mo[j * 64 + n];
        T[k][n] = acc;
    }
    for (int n = threadIdx.x; n < 64; n += 256) {
        float acc = mo_b[sl * 64 + n];
        for (int j = 0; j < 64; j++) acc += mi_b[sl * 192 + 128 + j] * Mo[j * 64 + n];
        bT[n] = acc;
    }
    __syncthreads();
    const float* W1 = w1 + sl * 64 * 128;
    for (int idx = threadIdx.x; idx < 64 * 128; idx += 256) {
        int k = idx >> 7, m = idx & 127;
        float acc = 0.f;
        for (int n = 0; n < 64; n++) acc += T[k][n] * W1[n * 128 + m];
        M1out[sl * 64 * 128 + idx] = acc;
    }
    for (int m = threadIdx.x; m < 128; m += 256) {
        float acc = b1[sl * 128 + m];
        for (int n = 0; n < 64; n++) acc += bT[n] * W1[n * 128 + m];
        bias1out[sl * 128 + m] = acc;
    }
}

// ---------------------------------------------------------------------------
// Pass 1: layer 0 over a T-chunk. BC=4, grid = 3*128 = 384 (single round).
// ---------------------------------------------------------------------------
__global__ __launch_bounds__(256, 2) void pass1_kernel(
    const float* __restrict__ x, const float* __restrict__ gw0,
    const float* __restrict__ gb0,
    const float* __restrict__ M1g, const float* __restrict__ bias1g,
    const float* __restrict__ w2g, const float* __restrict__ b2g,
    const float* __restrict__ lag, const float* __restrict__ lab,
    const float* __restrict__ log_, const float* __restrict__ lob,
    const float* __restrict__ rw0, const float* __restrict__ rb0,
    float* __restrict__ gstate,       // [3][512][4][64]
    float* __restrict__ inp_c,        // [3][512][CT][64]
    int t0) {
    const int tid = threadIdx.x;
    const int sIdx = blockIdx.x >> 7;
    const int gbase = (blockIdx.x & 127) * BC;
    const int W = tid >> 6, lane = tid & 63;
    const int q = lane >> 2, ks = lane & 3;
    const int oct = lane >> 3, ks8 = lane & 7;
    const int j = W * 16 + q;
    const int cM = W * 32 + q * 2;
    const int uD = W * 16 + oct * 2;

    const int Li = (sIdx == 0) ? 170 : (sIdx == 1 ? 512 : 256);
    const int st = (sIdx == 0) ? 342 : (sIdx == 1 ? 0 : 256);
    const float sc = (float)Li / 512.0f;

    __shared__ float s_x[2][BC][12];
    __shared__ float s_h[BC][64];
    __shared__ float s_ht[BC][64];
    __shared__ float s_z[BC][160];   // bank-padded (padi)
    __shared__ float s_t2[BC][64];
    __shared__ float s_rw0[768];

    // ---- register weights (f2-packed over k) ----
    const float* gw0s = gw0 + sIdx * IN0 * 256;
    float wx[12];
    f2 wg2[4][8], wm2[2][8], ww2[2][8];
#pragma unroll
    for (int g = 0; g < 4; g++)
#pragma unroll
        for (int d = 0; d < 3; d++) wx[g * 3 + d] = gw0s[(ks * 3 + d) * 256 + j + 64 * g];
#pragma unroll
    for (int g = 0; g < 4; g++)
#pragma unroll
        for (int kk = 0; kk < 8; kk++) {
            wg2[g][kk].x = gw0s[(12 + ks * 16 + 2 * kk) * 256 + j + 64 * g];
            wg2[g][kk].y = gw0s[(12 + ks * 16 + 2 * kk + 1) * 256 + j + 64 * g];
        }
    const float* M1s = M1g + (sIdx * 2 + 0) * 8192;
#pragma unroll
    for (int cc = 0; cc < 2; cc++)
#pragma unroll
        for (int kk = 0; kk < 8; kk++) {
            wm2[cc][kk].x = M1s[(ks * 16 + 2 * kk) * 128 + cM + cc];
            wm2[cc][kk].y = M1s[(ks * 16 + 2 * kk + 1) * 128 + cM + cc];
        }
    const float* w2s = w2g + (sIdx * 2 + 0) * 8192;
#pragma unroll
    for (int cc = 0; cc < 2; cc++)
#pragma unroll
        for (int kk = 0; kk < 8; kk++) {
            ww2[cc][kk].x = w2s[(ks8 * 16 + 2 * kk) * 64 + uD + cc];
            ww2[cc][kk].y = w2s[(ks8 * 16 + 2 * kk + 1) * 64 + uD + cc];
        }

    float h_gb[4];
#pragma unroll
    for (int g = 0; g < 4; g++) h_gb[g] = gb0[sIdx * 256 + j + 64 * g];
    float h_b1[2] = {bias1g[(sIdx * 2 + 0) * 128 + cM], bias1g[(sIdx * 2 + 0) * 128 + cM + 1]};
    float h_b2[2] = {b2g[(sIdx * 2 + 0) * 64 + uD], b2g[(sIdx * 2 + 0) * 64 + uD + 1]};
    int ei = (sIdx * 2 + 0) * 64 + lane;
    float eLag = lag[ei], eLab = lab[ei], eLog = log_[ei], eLob = lob[ei];
    float eRb0 = rb0[sIdx * 64 + lane];

    // ---- init ----
    for (int i = tid; i < 768; i += 256) s_rw0[i] = rw0[sIdx * 768 + i];
    {
        int b = tid >> 6, jj = tid & 63;  // 256 threads = BC*64 exactly
        s_h[b][jj] = (t0 == 0) ? 0.f : gstate[((size_t)(sIdx * Bn + gbase + b)) * 256 + jj];
    }
    float cS = (t0 == 0) ? 0.f
                         : gstate[((size_t)(sIdx * Bn + gbase + ks)) * 256 + 64 + j];
    if (tid < BC * 12) {
        int b = tid / 12, d = tid % 12;
        float srcp = fmaxf((t0 + 0.5f) * sc - 0.5f, 0.f);
        int i0 = (int)floorf(srcp); if (i0 > Li - 1) i0 = Li - 1;
        int i1 = i0 + 1; if (i1 > Li - 1) i1 = Li - 1;
        float w = srcp - (float)i0;
        int gb = gbase + b;
        s_x[0][b][d] = x[(gb * Ln + st + i0) * 12 + d] * (1.0f - w) + x[(gb * Ln + st + i1) * 12 + d] * w;
    }
    __syncthreads();

    for (int tt = 0; tt < CT; tt++) {
        const int sl = tt & 1;
        // ===== A: gates0 + cell =====
        float myF = 0, myI = 0, myG = 0, myO = 0;
#pragma unroll
        for (int b = 0; b < BC; b++) {
            const float4* hp = (const float4*)&s_h[b][ks * 16];
            float4 hv0 = hp[0], hv1 = hp[1], hv2 = hp[2], hv3 = hp[3];
            f2 hk2[8] = {{hv0.x, hv0.y}, {hv0.z, hv0.w}, {hv1.x, hv1.y}, {hv1.z, hv1.w},
                         {hv2.x, hv2.y}, {hv2.z, hv2.w}, {hv3.x, hv3.y}, {hv3.z, hv3.w}};
            float x0 = s_x[sl][b][ks * 3], x1 = s_x[sl][b][ks * 3 + 1], x2 = s_x[sl][b][ks * 3 + 2];
            float seed[4];
            f2 acc2[4];
#pragma unroll
            for (int g = 0; g < 4; g++) {
                float s0 = (ks == 0) ? h_gb[g] : 0.f;
                seed[g] = fmaf(wx[g * 3], x0, fmaf(wx[g * 3 + 1], x1, fmaf(wx[g * 3 + 2], x2, s0)));
                acc2[g] = (f2){0.f, 0.f};
            }
#pragma unroll
            for (int kk = 0; kk < 8; kk++) {
#pragma unroll
                for (int g = 0; g < 4; g++)
                    acc2[g] = fma2(wg2[g][kk], hk2[kk], acc2[g]);
            }
            float a0 = qsum(seed[0] + acc2[0].x + acc2[0].y);
            float a1 = qsum(seed[1] + acc2[1].x + acc2[1].y);
            float a2 = qsum(seed[2] + acc2[2].x + acc2[2].y);
            float a3 = qsum(seed[3] + acc2[3].x + acc2[3].y);
            if (ks == b) { myF = a0; myI = a1; myG = a2; myO = a3; }
        }
        {
            float cn = sigm(myF) * cS + sigm(myI) * tanhf(myG);
            cS = cn;
            s_ht[ks][j] = sigm(myO) * tanhf(cn);
        }
        __syncthreads();
        // ===== C: z = gelu(ht @ M1_0 + bias1) =====
        float z0 = 0, z1 = 0;
#pragma unroll
        for (int b = 0; b < BC; b++) {
            const float4* hp = (const float4*)&s_ht[b][ks * 16];
            float4 hv0 = hp[0], hv1 = hp[1], hv2 = hp[2], hv3 = hp[3];
            f2 hk2[8] = {{hv0.x, hv0.y}, {hv0.z, hv0.w}, {hv1.x, hv1.y}, {hv1.z, hv1.w},
                         {hv2.x, hv2.y}, {hv2.z, hv2.w}, {hv3.x, hv3.y}, {hv3.z, hv3.w}};
            f2 acc0 = (f2){0.f, 0.f}, acc1 = (f2){0.f, 0.f};
#pragma unroll
            for (int kk = 0; kk < 8; kk++) {
                acc0 = fma2(wm2[0][kk], hk2[kk], acc0);
                acc1 = fma2(wm2[1][kk], hk2[kk], acc1);
            }
            float s0 = (ks == 0) ? h_b1[0] : 0.f;
            float s1 = (ks == 0) ? h_b1[1] : 0.f;
            float a0 = qsum(s0 + acc0.x + acc0.y);
            float a1 = qsum(s1 + acc1.x + acc1.y);
            if (ks == b) { z0 = a0; z1 = a1; }
        }
        {
            int zc = padi(cM);
            s_z[ks][zc] = gelu_ex(z0);
            s_z[ks][zc + 1] = gelu_ex(z1);
        }
        __syncthreads();
        // ===== D: t2 = z @ w2_0 + b2 (octet) =====
#pragma unroll
        for (int b = 0; b < BC; b++) {
            const float4* zp = (const float4*)&s_z[b][ks8 * 20];  // padi(ks8*16)
            float4 zv0 = zp[0], zv1 = zp[1], zv2 = zp[2], zv3 = zp[3];
            f2 zk2[8] = {{zv0.x, zv0.y}, {zv0.z, zv0.w}, {zv1.x, zv1.y}, {zv1.z, zv1.w},
                         {zv2.x, zv2.y}, {zv2.z, zv2.w}, {zv3.x, zv3.y}, {zv3.z, zv3.w}};
            f2 acc0 = (f2){0.f, 0.f}, acc1 = (f2){0.f, 0.f};
#pragma unroll
            for (int kk = 0; kk < 8; kk++) {
                acc0 = fma2(ww2[0][kk], zk2[kk], acc0);
                acc1 = fma2(ww2[1][kk], zk2[kk], acc1);
            }
            float s0 = (ks8 == 0) ? h_b2[0] : 0.f;
            float s1 = (ks8 == 0) ? h_b2[1] : 0.f;
            float a0 = osum(s0 + acc0.x + acc0.y);
            float a1 = osum(s1 + acc1.x + acc1.y);
            if (ks8 == b) { s_t2[b][uD] = a0; s_t2[b][uD + 1] = a1; }
        }
        __syncthreads();
        // ===== E: all 4 waves (batch = W): LN chain + inp; then stage next x =====
        {
            const int bb = W;
            float v = s_t2[bb][lane];
            float m = redsum64(v) * (1.0f / 64.0f);
            float var = redsum64(v * v) * (1.0f / 64.0f) - m * m;
            float rs = rsqrtf(fmaxf(var, 0.0f) + 1e-5f);
            float a = (v - m) * rs * eLag + eLab;
            float y = a + s_h[bb][lane];
            float m2 = redsum64(y) * (1.0f / 64.0f);
            float var2 = redsum64(y * y) * (1.0f / 64.0f) - m2 * m2;
            float rs2 = rsqrtf(fmaxf(var2, 0.0f) + 1e-5f);
            float h0n = (y - m2) * rs2 * eLog + eLob;
            s_h[bb][lane] = h0n;
            float p = h0n + eRb0;
#pragma unroll
            for (int d = 0; d < 12; d++)
                p = fmaf(s_x[sl][bb][d], s_rw0[d * 64 + lane], p);
            inp_c[(((size_t)(sIdx * Bn + gbase + bb)) * CT + tt) * 64 + lane] = p;
            if (tt + 1 < CT && lane < 12) {
                int d = lane;
                int t = t0 + tt + 1;
                float srcp = fmaxf((t + 0.5f) * sc - 0.5f, 0.f);
                int i0 = (int)floorf(srcp); if (i0 > Li - 1) i0 = Li - 1;
                int i1 = i0 + 1; if (i1 > Li - 1) i1 = Li - 1;
                float w = srcp - (float)i0;
                int gb = gbase + bb;
                s_x[sl ^ 1][bb][d] = x[(gb * Ln + st + i0) * 12 + d] * (1.0f - w) +
                                     x[(gb * Ln + st + i1) * 12 + d] * w;
            }
        }
        __syncthreads();
    }
    // ---- writeback ----
    {
        int b = tid >> 6, jj = tid & 63;
        gstate[((size_t)(sIdx * Bn + gbase + b)) * 256 + jj] = s_h[b][jj];
    }
    gstate[((size_t)(sIdx * Bn + gbase + ks)) * 256 + 64 + j] = cS;
}

// ---------------------------------------------------------------------------
// G1R GEMM: G1R[row][0:256] = inp @ gw1_top + gb1 ; [256:320] = inp @ rw1 + rb1
// ---------------------------------------------------------------------------
__global__ __launch_bounds__(256) void g1r_kernel(
    const float* __restrict__ gw1, const float* __restrict__ gb1,
    const float* __restrict__ rw1, const float* __restrict__ rb1,
    const float* __restrict__ inp_c, float* __restrict__ G1R) {
    const int tid = threadIdx.x;
    const int s = blockIdx.x / 86;
    const int bb = blockIdx.x % 86;
    __shared__ __align__(16) float s_W[64 * 320];
    __shared__ __align__(16) float s_inT[64][36];

    for (int i = tid; i < 64 * 64; i += 256) {
        int k = i >> 6, cq = i & 63;
        ((float4*)&s_W[k * 320])[cq] = ((const float4*)(gw1 + (size_t)s * 128 * 256 + k * 256))[cq];
    }
    for (int i = tid; i < 64 * 16; i += 256) {
        int k = i >> 4, cq = i & 15;
        ((float4*)&s_W[k * 320 + 256])[cq] = ((const float4*)(rw1 + (size_t)s * 64 * 64 + k * 64))[cq];
    }
    const int c4 = tid & 63, rg = tid >> 6;
    float4 bias = *(const float4*)(gb1 + s * 256 + c4 * 4);
    float rbias = rb1[s * 64 + c4];

    const size_t sRow = (size_t)s * Bn * CT;
    for (int tile = 0; tile < 6; tile++) {
        int tIdx = bb * 6 + tile;
        if (tIdx >= 512) break;   // uniform per block
        int r0 = tIdx * 32;
        __syncthreads();
        for (int i = tid; i < 512; i += 256) {
            int r = i >> 4, kq = i & 15;
            float4 v = *(const float4*)(inp_c + (sRow + r0 + r) * 64 + kq * 4);
            s_inT[kq * 4 + 0][r] = v.x;
            s_inT[kq * 4 + 1][r] = v.y;
            s_inT[kq * 4 + 2][r] = v.z;
            s_inT[kq * 4 + 3][r] = v.w;
        }
        __syncthreads();
        float acc[8][4], accR[8];
#pragma unroll
        for (int r = 0; r < 8; r++) {
            acc[r][0] = bias.x; acc[r][1] = bias.y; acc[r][2] = bias.z; acc[r][3] = bias.w;
            accR[r] = rbias;
        }
        for (int k = 0; k < 64; k++) {
            float4 w = *(const float4*)&s_W[k * 320 + c4 * 4];
            float wR = s_W[k * 320 + 256 + c4];
            float4 iA = *(const float4*)&s_inT[k][rg * 8];
            float4 iB = *(const float4*)&s_inT[k][rg * 8 + 4];
            float in8[8] = {iA.x, iA.y, iA.z, iA.w, iB.x, iB.y, iB.z, iB.w};
#pragma unroll
            for (int r = 0; r < 8; r++) {
                acc[r][0] = fmaf(in8[r], w.x, acc[r][0]);
                acc[r][1] = fmaf(in8[r], w.y, acc[r][1]);
                acc[r][2] = fmaf(in8[r], w.z, acc[r][2]);
                acc[r][3] = fmaf(in8[r], w.w, acc[r][3]);
                accR[r] = fmaf(in8[r], wR, accR[r]);
            }
        }
#pragma unroll
        for (int r = 0; r < 8; r++) {
            size_t row = sRow + r0 + rg * 8 + r;
            float4 o; o.x = acc[r][0]; o.y = acc[r][1]; o.z = acc[r][2]; o.w = acc[r][3];
            *(float4*)(G1R + row * 320 + c4 * 4) = o;
            G1R[row * 320 + 256 + c4] = accR[r];
        }
    }
}

// ---------------------------------------------------------------------------
// Pass 2: layer 1 over a T-chunk. BC=4, grid 384; G1R read direct from global.
// ---------------------------------------------------------------------------
__global__ __launch_bounds__(256, 2) void pass2_kernel(
    const float* __restrict__ gw1,
    const float* __restrict__ M1g, const float* __restrict__ bias1g,
    const float* __restrict__ w2g, const float* __restrict__ b2g,
    const float* __restrict__ lag, const float* __restrict__ lab,
    const float* __restrict__ log_, const float* __restrict__ lob,
    const float* __restrict__ G1R,
    float* __restrict__ gstate,
    unsigned short* __restrict__ merged_c,
    int t0) {
    const int tid = threadIdx.x;
    const int sIdx = blockIdx.x >> 7;
    const int gbase = (blockIdx.x & 127) * BC;
    const int W = tid >> 6, lane = tid & 63;
    const int q = lane >> 2, ks = lane & 3;
    const int oct = lane >> 3, ks8 = lane & 7;
    const int j = W * 16 + q;
    const int cM = W * 32 + q * 2;
    const int uD = W * 16 + oct * 2;

    __shared__ float s_h[BC][64];
    __shared__ float s_ht[BC][64];
    __shared__ float s_z[BC][160];
    __shared__ float s_t2[BC][64];

    // ---- register weights (f2-packed) ----
    const float* gw1s = gw1 + (size_t)sIdx * 128 * 256;
    f2 wg2[4][8], wm2[2][8], ww2[2][8];
#pragma unroll
    for (int g = 0; g < 4; g++)
#pragma unroll
        for (int kk = 0; kk < 8; kk++) {
            wg2[g][kk].x = gw1s[(64 + ks * 16 + 2 * kk) * 256 + j + 64 * g];
            wg2[g][kk].y = gw1s[(64 + ks * 16 + 2 * kk + 1) * 256 + j + 64 * g];
        }
    const float* M1s = M1g + (sIdx * 2 + 1) * 8192;
#pragma unroll
    for (int cc = 0; cc < 2; cc++)
#pragma unroll
        for (int kk = 0; kk < 8; kk++) {
            wm2[cc][kk].x = M1s[(ks * 16 + 2 * kk) * 128 + cM + cc];
            wm2[cc][kk].y = M1s[(ks * 16 + 2 * kk + 1) * 128 + cM + cc];
        }
    const float* w2s = w2g + (sIdx * 2 + 1) * 8192;
#pragma unroll
    for (int cc = 0; cc < 2; cc++)
#pragma unroll
        for (int kk = 0; kk < 8; kk++) {
            ww2[cc][kk].x = w2s[(ks8 * 16 + 2 * kk) * 64 + uD + cc];
            ww2[cc][kk].y = w2s[(ks8 * 16 + 2 * kk + 1) * 64 + uD + cc];
        }

    float h_b1[2] = {bias1g[(sIdx * 2 + 1) * 128 + cM], bias1g[(sIdx * 2 + 1) * 128 + cM + 1]};
    float h_b2[2] = {b2g[(sIdx * 2 + 1) * 64 + uD], b2g[(sIdx * 2 + 1) * 64 + uD + 1]};
    int ei = (sIdx * 2 + 1) * 64 + lane;
    float eLag = lag[ei], eLab = lab[ei], eLog = log_[ei], eLob = lob[ei];

    // ---- init ----
    {
        int b = tid >> 6, jj = tid & 63;
        s_h[b][jj] = (t0 == 0) ? 0.f : gstate[((size_t)(sIdx * Bn + gbase + b)) * 256 + 128 + jj];
    }
    float cS = (t0 == 0) ? 0.f
                         : gstate[((size_t)(sIdx * Bn + gbase + ks)) * 256 + 192 + j];
    __syncthreads();

    const size_t rowBase = ((size_t)(sIdx * Bn + gbase)) * CT;

    for (int tt = 0; tt < CT; tt++) {
        // gate seeds from G1R (coalesced: c = ks*64 + j covers 0..255 per b)
        float g1rv[BC];
#pragma unroll
        for (int b = 0; b < BC; b++)
            g1rv[b] = G1R[(rowBase + (size_t)b * CT + tt) * 320 + ks * 64 + j];
        // ===== A: gates1 = G1R + h1 @ gw1_bot; cell =====
        float myF = 0, myI = 0, myG = 0, myO = 0;
#pragma unroll
        for (int b = 0; b < BC; b++) {
            const float4* hp = (const float4*)&s_h[b][ks * 16];
            float4 hv0 = hp[0], hv1 = hp[1], hv2 = hp[2], hv3 = hp[3];
            f2 hk2[8] = {{hv0.x, hv0.y}, {hv0.z, hv0.w}, {hv1.x, hv1.y}, {hv1.z, hv1.w},
                         {hv2.x, hv2.y}, {hv2.z, hv2.w}, {hv3.x, hv3.y}, {hv3.z, hv3.w}};
            f2 acc2[4];
#pragma unroll
            for (int g = 0; g < 4; g++) acc2[g] = (f2){0.f, 0.f};
#pragma unroll
            for (int kk = 0; kk < 8; kk++) {
#pragma unroll
                for (int g = 0; g < 4; g++)
                    acc2[g] = fma2(wg2[g][kk], hk2[kk], acc2[g]);
            }
            float a0 = qsum(((ks == 0) ? g1rv[b] : 0.f) + acc2[0].x + acc2[0].y);
            float a1 = qsum(((ks == 1) ? g1rv[b] : 0.f) + acc2[1].x + acc2[1].y);
            float a2 = qsum(((ks == 2) ? g1rv[b] : 0.f) + acc2[2].x + acc2[2].y);
            float a3 = qsum(((ks == 3) ? g1rv[b] : 0.f) + acc2[3].x + acc2[3].y);
            if (ks == b) { myF = a0; myI = a1; myG = a2; myO = a3; }
        }
        {
            float cn = sigm(myF) * cS + sigm(myI) * tanhf(myG);
            cS = cn;
            s_ht[ks][j] = sigm(myO) * tanhf(cn);
        }
        __syncthreads();
        // ===== C: z = gelu(ht @ M1_1 + bias1) =====
        float z0 = 0, z1 = 0;
#pragma unroll
        for (int b = 0; b < BC; b++) {
            const float4* hp = (const float4*)&s_ht[b][ks * 16];
            float4 hv0 = hp[0], hv1 = hp[1], hv2 = hp[2], hv3 = hp[3];
            f2 hk2[8] = {{hv0.x, hv0.y}, {hv0.z, hv0.w}, {hv1.x, hv1.y}, {hv1.z, hv1.w},
                         {hv2.x, hv2.y}, {hv2.z, hv2.w}, {hv3.x, hv3.y}, {hv3.z, hv3.w}};
            f2 acc0 = (f2){0.f, 0.f}, acc1 = (f2){0.f, 0.f};
#pragma unroll
            for (int kk = 0; kk < 8; kk++) {
                acc0 = fma2(wm2[0][kk], hk2[kk], acc0);
                acc1 = fma2(wm2[1][kk], hk2[kk], acc1);
            }
            float s0 = (ks == 0) ? h_b1[0] : 0.f;
            float s1 = (ks == 0) ? h_b1[1] : 0.f;
            float a0 = qsum(s0 + acc0.x + acc0.y);
            float a1 = qsum(s1 + acc1.x + acc1.y);
            if (ks == b) { z0 = a0; z1 = a1; }
        }
        {
            int zc = padi(cM);
            s_z[ks][zc] = gelu_ex(z0);
            s_z[ks][zc + 1] = gelu_ex(z1);
        }
        __syncthreads();
        // ===== D: t2 = z @ w2_1 + b2 (octet) =====
#pragma unroll
        for (int b = 0; b < BC; b++) {
            const float4* zp = (const float4*)&s_z[b][ks8 * 20];
            float4 zv0 = zp[0], zv1 = zp[1], zv2 = zp[2], zv3 = zp[3];
            f2 zk2[8] = {{zv0.x, zv0.y}, {zv0.z, zv0.w}, {zv1.x, zv1.y}, {zv1.z, zv1.w},
                         {zv2.x, zv2.y}, {zv2.z, zv2.w}, {zv3.x, zv3.y}, {zv3.z, zv3.w}};
            f2 acc0 = (f2){0.f, 0.f}, acc1 = (f2){0.f, 0.f};
#pragma unroll
            for (int kk = 0; kk < 8; kk++) {
                acc0 = fma2(ww2[0][kk], zk2[kk], acc0);
                acc1 = fma2(ww2[1][kk], zk2[kk], acc1);
            }
            float s0 = (ks8 == 0) ? h_b2[0] : 0.f;
            float s1 = (ks8 == 0) ? h_b2[1] : 0.f;
            float a0 = osum(s0 + acc0.x + acc0.y);
            float a1 = osum(s1 + acc1.x + acc1.y);
            if (ks8 == b) { s_t2[b][uD] = a0; s_t2[b][uD + 1] = a1; }
        }
        __syncthreads();
        // ===== E: all 4 waves (batch = W): LN chain -> h1new; out = h1new + R1 =====
        {
            const int bb = W;
            float r = G1R[(rowBase + (size_t)bb * CT + tt) * 320 + 256 + lane];
            float v = s_t2[bb][lane];
            float m = redsum64(v) * (1.0f / 64.0f);
            float var = redsum64(v * v) * (1.0f / 64.0f) - m * m;
            float rs = rsqrtf(fmaxf(var, 0.0f) + 1e-5f);
            float a = (v - m) * rs * eLag + eLab;
            float y = a + s_h[bb][lane];
            float m2 = redsum64(y) * (1.0f / 64.0f);
            float var2 = redsum64(y * y) * (1.0f / 64.0f) - m2 * m2;
            float rs2 = rsqrtf(fmaxf(var2, 0.0f) + 1e-5f);
            float h1n = (y - m2) * rs2 * eLog + eLob;
            s_h[bb][lane] = h1n;
            merged_c[(((size_t)(sIdx * Bn + gbase + bb)) * CT + tt) * 64 + lane] = f2u(h1n + r);
        }
        __syncthreads();
    }
    // ---- writeback ----
    {
        int b = tid >> 6, jj = tid & 63;
        gstate[((size_t)(sIdx * Bn + gbase + b)) * 256 + 128 + jj] = s_h[b][jj];
    }
    gstate[((size_t)(sIdx * Bn + gbase + ks)) * 256 + 192 + j] = cS;
}

// ---------------------------------------------------------------------------
// Combine (per chunk): softmax over scales, weighted sum -> out
// ---------------------------------------------------------------------------
__global__ __launch_bounds__(256) void combine_kernel(
    const unsigned short* __restrict__ merged_c,
    const float* __restrict__ attn_w,
    void* __restrict__ outv, const int* __restrict__ flag, int t0) {
    int wid = (blockIdx.x << 2) + (threadIdx.x >> 6);
    int lane = threadIdx.x & 63;
    int b = wid / CT, tt = wid % CT;
    float aw = attn_w[lane];
    size_t stride = (size_t)Bn * CT * 64;
    size_t base = (((size_t)b) * CT + tt) * 64 + lane;
    float m0 = u2f(merged_c[base]);
    float m1 = u2f(merged_c[base + stride]);
    float m2 = u2f(merged_c[base + 2 * stride]);
    float e0 = redsum64(m0 * aw);
    float e1 = redsum64(m1 * aw);
    float e2 = redsum64(m2 * aw);
    float mx = fmaxf(e0, fmaxf(e1, e2));
    float x0 = expf(e0 - mx), x1 = expf(e1 - mx), x2 = expf(e2 - mx);
    float inv = 1.0f / (x0 + x1 + x2);
    float val = (x0 * m0 + x1 * m1 + x2 * m2) * inv;
    size_t ob = (((size_t)b) * Ln + t0 + tt) * 64 + lane;
    if (*flag) ((float*)outv)[ob] = val;
    else ((unsigned short*)outv)[ob] = f2u(val);
}

extern "C" void kernel_launch(void* const* d_in, const int* in_sizes, int n_in,
                              void* d_out, int out_size, void* d_ws, size_t ws_size,
                              hipStream_t stream) {
    (void)out_size; (void)ws_size;
    int* flag = (int*)d_ws;
    float* canon = (float*)((char*)d_ws + 16);

    ConvArgs ca;
    size_t tot = 0;
    unsigned nblocks = 0;
    for (int i = 0; i < NIN; i++) {
        ca.src[i] = d_in[i];
        ca.dstOff[i] = (unsigned)tot;
        unsigned n = (unsigned)in_sizes[i];
        ca.n[i] = n;
        ca.blockStart[i] = nblocks;
        nblocks += (n + 2047) / 2048;
        tot += n;
    }
    ca.blockStart[NIN] = nblocks;

    size_t canonBytes = (tot * 4 + 15) & ~(size_t)15;
    char* p = (char*)d_ws + 16 + canonBytes;
    float* M1 = (float*)p;       p += (size_t)3 * 2 * 64 * 128 * 4;
    float* bias1 = (float*)p;    p += (size_t)3 * 2 * 128 * 4;
    float* gstate = (float*)p;   p += (size_t)3 * 512 * 4 * 64 * 4;
    float* inp_c = (float*)p;    p += (size_t)3 * 512 * CT * 64 * 4;
    float* G1R = (float*)p;      p += (size_t)3 * 512 * CT * 320 * 4;
    p = (char*)(((uintptr_t)p + 15) & ~(uintptr_t)15);
    unsigned short* merged_c = (unsigned short*)p;

    const float* x    = canon + ca.dstOff[0];
    const float* gw0  = canon + ca.dstOff[1];
    const float* gb0  = canon + ca.dstOff[2];
    const float* gw1  = canon + ca.dstOff[3];
    const float* gb1  = canon + ca.dstOff[4];
    const float* mi_w = canon + ca.dstOff[5];
    const float* mi_b = canon + ca.dstOff[6];
    const float* mo_w = canon + ca.dstOff[7];
    const float* mo_b = canon + ca.dstOff[8];
    const float* w1   = canon + ca.dstOff[9];
    const float* b1   = canon + ca.dstOff[10];
    const float* w2   = canon + ca.dstOff[11];
    const float* b2   = canon + ca.dstOff[12];
    const float* lag  = canon + ca.dstOff[13];
    const float* lab  = canon + ca.dstOff[14];
    const float* log_ = canon + ca.dstOff[15];
    const float* lob  = canon + ca.dstOff[16];
    const float* rw0  = canon + ca.dstOff[17];
    const float* rb0  = canon + ca.dstOff[18];
    const float* rw1  = canon + ca.dstOff[19];
    const float* rb1  = canon + ca.dstOff[20];
    const float* attn_w = canon + ca.dstOff[21];

    detect_kernel<<<dim3(1), dim3(256), 0, stream>>>((const unsigned short*)d_in[0], flag);
    convert_kernel<<<dim3(nblocks), dim3(256), 0, stream>>>(ca, canon, flag);
    fuse_kernel<<<dim3(6), dim3(256), 0, stream>>>(mi_w, mi_b, mo_w, mo_b, w1, b1, M1, bias1);

    for (int c = 0; c < NCHUNK; c++) {
        int t0 = c * CT;
        pass1_kernel<<<dim3(Sn * (Bn / BC)), dim3(256), 0, stream>>>(
            x, gw0, gb0, M1, bias1, w2, b2, lag, lab, log_, lob,
            rw0, rb0, gstate, inp_c, t0);
        g1r_kernel<<<dim3(3 * 86), dim3(256), 0, stream>>>(
            gw1, gb1, rw1, rb1, inp_c, G1R);
        pass2_kernel<<<dim3(Sn * (Bn / BC)), dim3(256), 0, stream>>>(
            gw1, M1, bias1, w2, b2, lag, lab, log_, lob,
            G1R, gstate, merged_c, t0);
        combine_kernel<<<dim3(Bn * CT / 4), dim3(256), 0, stream>>>(
            merged_c, attn_w, d_out, flag, t0);
    }
}

// Round 9
// 4874.049 us; speedup vs baseline: 1.6179x; 1.1789x over previous
//
#include <hip/hip_runtime.h>
#include <hip/hip_bf16.h>
#include <math.h>

// Problem constants
#define Sn 3
#define Hn 64
#define Dn 12
#define Bn 512
#define Ln 512
#define BC 4            // batch elems per workgroup (one per wave for E-phase)
#define IN0 76          // D + H
#define NIN 22
#define CT 32           // timesteps per chunk
#define NCHUNK (Ln / CT)
#define P2BLK 384       // pass2 block count in fused kernel
#define G1RBLK 258      // g1r block count in post kernel

using bf16 = __hip_bfloat16;
typedef __attribute__((ext_vector_type(2))) float f2;

__device__ __forceinline__ f2 fma2(f2 a, f2 b, f2 c) {
#if __has_builtin(__builtin_elementwise_fma)
    return __builtin_elementwise_fma(a, b, c);
#else
    f2 r; r.x = fmaf(a.x, b.x, c.x); r.y = fmaf(a.y, b.y, c.y); return r;
#endif
}

__device__ __forceinline__ float u2f(unsigned short x) {
    return __uint_as_float(((unsigned int)x) << 16);
}
__device__ __forceinline__ unsigned short f2u(float f) {
    bf16 h = __float2bfloat16(f);
    unsigned short u;
    __builtin_memcpy(&u, &h, 2);
    return u;
}
__device__ __forceinline__ float sigm(float x) { return 1.0f / (1.0f + expf(-x)); }
__device__ __forceinline__ float gelu_ex(float x) { return 0.5f * x * (1.0f + erff(x * 0.70710678118654752f)); }
__device__ __forceinline__ int padi(int c) { return c + ((c >> 4) << 2); }

__device__ __forceinline__ float redsum64(float v) {
    v += __shfl_xor(v, 32, 64);
    v += __shfl_xor(v, 16, 64);
    v += __shfl_xor(v, 8, 64);
    v += __shfl_xor(v, 4, 64);
    v += __shfl_xor(v, 2, 64);
    v += __shfl_xor(v, 1, 64);
    return v;
}

template <int CTRL>
__device__ __forceinline__ float qp(float v) {
    return __int_as_float(__builtin_amdgcn_update_dpp(0, __float_as_int(v), CTRL, 0xF, 0xF, true));
}
__device__ __forceinline__ float qsum(float v) {
    v += qp<0xB1>(v);
    v += qp<0x4E>(v);
    return v;
}
__device__ __forceinline__ float osum(float v) {
    v = qsum(v);
    v += __int_as_float(__builtin_amdgcn_ds_swizzle(__float_as_int(v), 0x101F));
    return v;
}

// ---------------------------------------------------------------------------
// dtype detection (flag=1 -> inputs fp32)
// ---------------------------------------------------------------------------
__global__ __launch_bounds__(256) void detect_kernel(const unsigned short* __restrict__ xr,
                                                     int* __restrict__ flag) {
    __shared__ int sh[4];
    int tid = threadIdx.x;
    int cnt = 0;
    for (int i = tid; i < 2048; i += 256) {
        unsigned e = (xr[i] >> 7) & 0xFF;
        if (e >= 110 && e <= 133) cnt++;
    }
    for (int o = 32; o > 0; o >>= 1) cnt += __shfl_xor(cnt, o, 64);
    if ((tid & 63) == 0) sh[tid >> 6] = cnt;
    __syncthreads();
    if (tid == 0) {
        int tot = sh[0] + sh[1] + sh[2] + sh[3];
        *flag = (tot < 1640) ? 1 : 0;
    }
}

// ---------------------------------------------------------------------------
// canonicalize all inputs to fp32 in ws
// ---------------------------------------------------------------------------
struct ConvArgs {
    const void* src[NIN];
    unsigned dstOff[NIN];
    unsigned n[NIN];
    unsigned blockStart[NIN + 1];
};

__global__ __launch_bounds__(256) void convert_kernel(ConvArgs a, float* __restrict__ dst,
                                                      const int* __restrict__ flag) {
    int bid = blockIdx.x;
    int i = 0;
    while (i < NIN - 1 && bid >= (int)a.blockStart[i + 1]) i++;
    unsigned lb = (unsigned)bid - a.blockStart[i];
    unsigned base = lb * 2048 + threadIdx.x;
    unsigned n = a.n[i];
    float* d = dst + a.dstOff[i];
    bool isf32 = (*flag != 0);
    const float* sf = (const float*)a.src[i];
    const unsigned short* su = (const unsigned short*)a.src[i];
#pragma unroll
    for (int e = 0; e < 8; e++) {
        unsigned idx = base + e * 256;
        if (idx < n) d[idx] = isf32 ? sf[idx] : u2f(su[idx]);
    }
}

// ---------------------------------------------------------------------------
// Setup: fuse  M1 = (mi_w[:,128:192] @ mo_w) @ w1 ; bias1 chain
// ---------------------------------------------------------------------------
__global__ __launch_bounds__(256) void fuse_kernel(
    const float* __restrict__ mi_w, const float* __restrict__ mi_b,
    const float* __restrict__ mo_w, const float* __restrict__ mo_b,
    const float* __restrict__ w1, const float* __restrict__ b1,
    float* __restrict__ M1out, float* __restrict__ bias1out) {
    int sl = blockIdx.x;  // 0..5
    __shared__ float T[64][64];
    __shared__ float bT[64];
    const float* Mv = mi_w + sl * 64 * 192;
    const float* Mo = mo_w + sl * 64 * 64;
    for (int idx = threadIdx.x; idx < 64 * 64; idx += 256) {
        int k = idx >> 6, n = idx & 63;
        float acc = 0.f;
        for (int j = 0; j < 64; j++) acc += Mv[k * 192 + 128 + j] * Mo[j * 64 + n];
        T[k][n] = acc;
    }
    for (int n = threadIdx.x; n < 64; n += 256) {
        float acc = mo_b[sl * 64 + n];
        for (int j = 0; j < 64; j++) acc += mi_b[sl * 192 + 128 + j] * Mo[j * 64 + n];
        bT[n] = acc;
    }
    __syncthreads();
    const float* W1 = w1 + sl * 64 * 128;
    for (int idx = threadIdx.x; idx < 64 * 128; idx += 256) {
        int k = idx >> 7, m = idx & 127;
        float acc = 0.f;
        for (int n = 0; n < 64; n++) acc += T[k][n] * W1[n * 128 + m];
        M1out[sl * 64 * 128 + idx] = acc;
    }
    for (int m = threadIdx.x; m < 128; m += 256) {
        float acc = b1[sl * 128 + m];
        for (int n = 0; n < 64; n++) acc += bT[n] * W1[n * 128 + m];
        bias1out[sl * 128 + m] = acc;
    }
}

// ---------------------------------------------------------------------------
// Pass 1 body: layer 0 over a T-chunk. bid in [0,384).
// ---------------------------------------------------------------------------
__device__ __forceinline__ void pass1_body(
    int bid,
    const float* __restrict__ x, const float* __restrict__ gw0,
    const float* __restrict__ gb0,
    const float* __restrict__ M1g, const float* __restrict__ bias1g,
    const float* __restrict__ w2g, const float* __restrict__ b2g,
    const float* __restrict__ lag, const float* __restrict__ lab,
    const float* __restrict__ log_, const float* __restrict__ lob,
    const float* __restrict__ rw0, const float* __restrict__ rb0,
    float* __restrict__ gstate, float* __restrict__ inp_c, int t0) {
    const int tid = threadIdx.x;
    const int sIdx = bid >> 7;
    const int gbase = (bid & 127) * BC;
    const int W = tid >> 6, lane = tid & 63;
    const int q = lane >> 2, ks = lane & 3;
    const int oct = lane >> 3, ks8 = lane & 7;
    const int j = W * 16 + q;
    const int cM = W * 32 + q * 2;
    const int uD = W * 16 + oct * 2;

    const int Li = (sIdx == 0) ? 170 : (sIdx == 1 ? 512 : 256);
    const int st = (sIdx == 0) ? 342 : (sIdx == 1 ? 0 : 256);
    const float sc = (float)Li / 512.0f;

    __shared__ float s_x[2][BC][12];
    __shared__ float s_h[BC][64];
    __shared__ float s_ht[BC][64];
    __shared__ float s_z[BC][160];
    __shared__ float s_t2[BC][64];
    __shared__ float s_rw0[768];

    const float* gw0s = gw0 + sIdx * IN0 * 256;
    float wx[12];
    f2 wg2[4][8], wm2[2][8], ww2[2][8];
#pragma unroll
    for (int g = 0; g < 4; g++)
#pragma unroll
        for (int d = 0; d < 3; d++) wx[g * 3 + d] = gw0s[(ks * 3 + d) * 256 + j + 64 * g];
#pragma unroll
    for (int g = 0; g < 4; g++)
#pragma unroll
        for (int kk = 0; kk < 8; kk++) {
            wg2[g][kk].x = gw0s[(12 + ks * 16 + 2 * kk) * 256 + j + 64 * g];
            wg2[g][kk].y = gw0s[(12 + ks * 16 + 2 * kk + 1) * 256 + j + 64 * g];
        }
    const float* M1s = M1g + (sIdx * 2 + 0) * 8192;
#pragma unroll
    for (int cc = 0; cc < 2; cc++)
#pragma unroll
        for (int kk = 0; kk < 8; kk++) {
            wm2[cc][kk].x = M1s[(ks * 16 + 2 * kk) * 128 + cM + cc];
            wm2[cc][kk].y = M1s[(ks * 16 + 2 * kk + 1) * 128 + cM + cc];
        }
    const float* w2s = w2g + (sIdx * 2 + 0) * 8192;
#pragma unroll
    for (int cc = 0; cc < 2; cc++)
#pragma unroll
        for (int kk = 0; kk < 8; kk++) {
            ww2[cc][kk].x = w2s[(ks8 * 16 + 2 * kk) * 64 + uD + cc];
            ww2[cc][kk].y = w2s[(ks8 * 16 + 2 * kk + 1) * 64 + uD + cc];
        }

    float h_gb[4];
#pragma unroll
    for (int g = 0; g < 4; g++) h_gb[g] = gb0[sIdx * 256 + j + 64 * g];
    float h_b1[2] = {bias1g[(sIdx * 2 + 0) * 128 + cM], bias1g[(sIdx * 2 + 0) * 128 + cM + 1]};
    float h_b2[2] = {b2g[(sIdx * 2 + 0) * 64 + uD], b2g[(sIdx * 2 + 0) * 64 + uD + 1]};
    int ei = (sIdx * 2 + 0) * 64 + lane;
    float eLag = lag[ei], eLab = lab[ei], eLog = log_[ei], eLob = lob[ei];
    float eRb0 = rb0[sIdx * 64 + lane];

    for (int i = tid; i < 768; i += 256) s_rw0[i] = rw0[sIdx * 768 + i];
    {
        int b = tid >> 6, jj = tid & 63;
        s_h[b][jj] = (t0 == 0) ? 0.f : gstate[((size_t)(sIdx * Bn + gbase + b)) * 256 + jj];
    }
    float cS = (t0 == 0) ? 0.f
                         : gstate[((size_t)(sIdx * Bn + gbase + ks)) * 256 + 64 + j];
    if (tid < BC * 12) {
        int b = tid / 12, d = tid % 12;
        float srcp = fmaxf((t0 + 0.5f) * sc - 0.5f, 0.f);
        int i0 = (int)floorf(srcp); if (i0 > Li - 1) i0 = Li - 1;
        int i1 = i0 + 1; if (i1 > Li - 1) i1 = Li - 1;
        float w = srcp - (float)i0;
        int gb = gbase + b;
        s_x[0][b][d] = x[(gb * Ln + st + i0) * 12 + d] * (1.0f - w) + x[(gb * Ln + st + i1) * 12 + d] * w;
    }
    __syncthreads();

    for (int tt = 0; tt < CT; tt++) {
        const int sl = tt & 1;
        // ===== A: gates0 + cell =====
        float myF = 0, myI = 0, myG = 0, myO = 0;
#pragma unroll
        for (int b = 0; b < BC; b++) {
            const float4* hp = (const float4*)&s_h[b][ks * 16];
            float4 hv0 = hp[0], hv1 = hp[1], hv2 = hp[2], hv3 = hp[3];
            f2 hk2[8] = {{hv0.x, hv0.y}, {hv0.z, hv0.w}, {hv1.x, hv1.y}, {hv1.z, hv1.w},
                         {hv2.x, hv2.y}, {hv2.z, hv2.w}, {hv3.x, hv3.y}, {hv3.z, hv3.w}};
            float x0 = s_x[sl][b][ks * 3], x1 = s_x[sl][b][ks * 3 + 1], x2 = s_x[sl][b][ks * 3 + 2];
            float seed[4];
            f2 acc2[4];
#pragma unroll
            for (int g = 0; g < 4; g++) {
                float s0 = (ks == 0) ? h_gb[g] : 0.f;
                seed[g] = fmaf(wx[g * 3], x0, fmaf(wx[g * 3 + 1], x1, fmaf(wx[g * 3 + 2], x2, s0)));
                acc2[g] = (f2){0.f, 0.f};
            }
#pragma unroll
            for (int kk = 0; kk < 8; kk++) {
#pragma unroll
                for (int g = 0; g < 4; g++)
                    acc2[g] = fma2(wg2[g][kk], hk2[kk], acc2[g]);
            }
            float a0 = qsum(seed[0] + acc2[0].x + acc2[0].y);
            float a1 = qsum(seed[1] + acc2[1].x + acc2[1].y);
            float a2 = qsum(seed[2] + acc2[2].x + acc2[2].y);
            float a3 = qsum(seed[3] + acc2[3].x + acc2[3].y);
            if (ks == b) { myF = a0; myI = a1; myG = a2; myO = a3; }
        }
        {
            float cn = sigm(myF) * cS + sigm(myI) * tanhf(myG);
            cS = cn;
            s_ht[ks][j] = sigm(myO) * tanhf(cn);
        }
        __syncthreads();
        // ===== C: z = gelu(ht @ M1_0 + bias1) =====
        float z0 = 0, z1 = 0;
#pragma unroll
        for (int b = 0; b < BC; b++) {
            const float4* hp = (const float4*)&s_ht[b][ks * 16];
            float4 hv0 = hp[0], hv1 = hp[1], hv2 = hp[2], hv3 = hp[3];
            f2 hk2[8] = {{hv0.x, hv0.y}, {hv0.z, hv0.w}, {hv1.x, hv1.y}, {hv1.z, hv1.w},
                         {hv2.x, hv2.y}, {hv2.z, hv2.w}, {hv3.x, hv3.y}, {hv3.z, hv3.w}};
            f2 acc0 = (f2){0.f, 0.f}, acc1 = (f2){0.f, 0.f};
#pragma unroll
            for (int kk = 0; kk < 8; kk++) {
                acc0 = fma2(wm2[0][kk], hk2[kk], acc0);
                acc1 = fma2(wm2[1][kk], hk2[kk], acc1);
            }
            float s0 = (ks == 0) ? h_b1[0] : 0.f;
            float s1 = (ks == 0) ? h_b1[1] : 0.f;
            float a0 = qsum(s0 + acc0.x + acc0.y);
            float a1 = qsum(s1 + acc1.x + acc1.y);
            if (ks == b) { z0 = a0; z1 = a1; }
        }
        {
            int zc = padi(cM);
            s_z[ks][zc] = gelu_ex(z0);
            s_z[ks][zc + 1] = gelu_ex(z1);
        }
        __syncthreads();
        // ===== D: t2 = z @ w2_0 + b2 (octet) =====
#pragma unroll
        for (int b = 0; b < BC; b++) {
            const float4* zp = (const float4*)&s_z[b][ks8 * 20];
            float4 zv0 = zp[0], zv1 = zp[1], zv2 = zp[2], zv3 = zp[3];
            f2 zk2[8] = {{zv0.x, zv0.y}, {zv0.z, zv0.w}, {zv1.x, zv1.y}, {zv1.z, zv1.w},
                         {zv2.x, zv2.y}, {zv2.z, zv2.w}, {zv3.x, zv3.y}, {zv3.z, zv3.w}};
            f2 acc0 = (f2){0.f, 0.f}, acc1 = (f2){0.f, 0.f};
#pragma unroll
            for (int kk = 0; kk < 8; kk++) {
                acc0 = fma2(ww2[0][kk], zk2[kk], acc0);
                acc1 = fma2(ww2[1][kk], zk2[kk], acc1);
            }
            float s0 = (ks8 == 0) ? h_b2[0] : 0.f;
            float s1 = (ks8 == 0) ? h_b2[1] : 0.f;
            float a0 = osum(s0 + acc0.x + acc0.y);
            float a1 = osum(s1 + acc1.x + acc1.y);
            if (ks8 == b) { s_t2[b][uD] = a0; s_t2[b][uD + 1] = a1; }
        }
        __syncthreads();
        // ===== E =====
        {
            const int bb = W;
            float v = s_t2[bb][lane];
            float m = redsum64(v) * (1.0f / 64.0f);
            float var = redsum64(v * v) * (1.0f / 64.0f) - m * m;
            float rs = rsqrtf(fmaxf(var, 0.0f) + 1e-5f);
            float a = (v - m) * rs * eLag + eLab;
            float y = a + s_h[bb][lane];
            float m2 = redsum64(y) * (1.0f / 64.0f);
            float var2 = redsum64(y * y) * (1.0f / 64.0f) - m2 * m2;
            float rs2 = rsqrtf(fmaxf(var2, 0.0f) + 1e-5f);
            float h0n = (y - m2) * rs2 * eLog + eLob;
            s_h[bb][lane] = h0n;
            float p = h0n + eRb0;
#pragma unroll
            for (int d = 0; d < 12; d++)
                p = fmaf(s_x[sl][bb][d], s_rw0[d * 64 + lane], p);
            inp_c[(((size_t)(sIdx * Bn + gbase + bb)) * CT + tt) * 64 + lane] = p;
            if (tt + 1 < CT && lane < 12) {
                int d = lane;
                int t = t0 + tt + 1;
                float srcp = fmaxf((t + 0.5f) * sc - 0.5f, 0.f);
                int i0 = (int)floorf(srcp); if (i0 > Li - 1) i0 = Li - 1;
                int i1 = i0 + 1; if (i1 > Li - 1) i1 = Li - 1;
                float w = srcp - (float)i0;
                int gb = gbase + bb;
                s_x[sl ^ 1][bb][d] = x[(gb * Ln + st + i0) * 12 + d] * (1.0f - w) +
                                     x[(gb * Ln + st + i1) * 12 + d] * w;
            }
        }
        __syncthreads();
    }
    {
        int b = tid >> 6, jj = tid & 63;
        gstate[((size_t)(sIdx * Bn + gbase + b)) * 256 + jj] = s_h[b][jj];
    }
    gstate[((size_t)(sIdx * Bn + gbase + ks)) * 256 + 64 + j] = cS;
}

// ---------------------------------------------------------------------------
// Pass 2 body: layer 1 over a T-chunk. bid in [0,384).
// ---------------------------------------------------------------------------
__device__ __forceinline__ void pass2_body(
    int bid,
    const float* __restrict__ gw1,
    const float* __restrict__ M1g, const float* __restrict__ bias1g,
    const float* __restrict__ w2g, const float* __restrict__ b2g,
    const float* __restrict__ lag, const float* __restrict__ lab,
    const float* __restrict__ log_, const float* __restrict__ lob,
    const float* __restrict__ G1R, float* __restrict__ gstate,
    unsigned short* __restrict__ merged_c, int t0) {
    const int tid = threadIdx.x;
    const int sIdx = bid >> 7;
    const int gbase = (bid & 127) * BC;
    const int W = tid >> 6, lane = tid & 63;
    const int q = lane >> 2, ks = lane & 3;
    const int oct = lane >> 3, ks8 = lane & 7;
    const int j = W * 16 + q;
    const int cM = W * 32 + q * 2;
    const int uD = W * 16 + oct * 2;

    __shared__ float p2_h[BC][64];
    __shared__ float p2_ht[BC][64];
    __shared__ float p2_z[BC][160];
    __shared__ float p2_t2[BC][64];

    const float* gw1s = gw1 + (size_t)sIdx * 128 * 256;
    f2 wg2[4][8], wm2[2][8], ww2[2][8];
#pragma unroll
    for (int g = 0; g < 4; g++)
#pragma unroll
        for (int kk = 0; kk < 8; kk++) {
            wg2[g][kk].x = gw1s[(64 + ks * 16 + 2 * kk) * 256 + j + 64 * g];
            wg2[g][kk].y = gw1s[(64 + ks * 16 + 2 * kk + 1) * 256 + j + 64 * g];
        }
    const float* M1s = M1g + (sIdx * 2 + 1) * 8192;
#pragma unroll
    for (int cc = 0; cc < 2; cc++)
#pragma unroll
        for (int kk = 0; kk < 8; kk++) {
            wm2[cc][kk].x = M1s[(ks * 16 + 2 * kk) * 128 + cM + cc];
            wm2[cc][kk].y = M1s[(ks * 16 + 2 * kk + 1) * 128 + cM + cc];
        }
    const float* w2s = w2g + (sIdx * 2 + 1) * 8192;
#pragma unroll
    for (int cc = 0; cc < 2; cc++)
#pragma unroll
        for (int kk = 0; kk < 8; kk++) {
            ww2[cc][kk].x = w2s[(ks8 * 16 + 2 * kk) * 64 + uD + cc];
            ww2[cc][kk].y = w2s[(ks8 * 16 + 2 * kk + 1) * 64 + uD + cc];
        }

    float h_b1[2] = {bias1g[(sIdx * 2 + 1) * 128 + cM], bias1g[(sIdx * 2 + 1) * 128 + cM + 1]};
    float h_b2[2] = {b2g[(sIdx * 2 + 1) * 64 + uD], b2g[(sIdx * 2 + 1) * 64 + uD + 1]};
    int ei = (sIdx * 2 + 1) * 64 + lane;
    float eLag = lag[ei], eLab = lab[ei], eLog = log_[ei], eLob = lob[ei];

    {
        int b = tid >> 6, jj = tid & 63;
        p2_h[b][jj] = (t0 == 0) ? 0.f : gstate[((size_t)(sIdx * Bn + gbase + b)) * 256 + 128 + jj];
    }
    float cS = (t0 == 0) ? 0.f
                         : gstate[((size_t)(sIdx * Bn + gbase + ks)) * 256 + 192 + j];
    __syncthreads();

    const size_t rowBase = ((size_t)(sIdx * Bn + gbase)) * CT;

    for (int tt = 0; tt < CT; tt++) {
        float g1rv[BC];
#pragma unroll
        for (int b = 0; b < BC; b++)
            g1rv[b] = G1R[(rowBase + (size_t)b * CT + tt) * 320 + ks * 64 + j];
        // ===== A =====
        float myF = 0, myI = 0, myG = 0, myO = 0;
#pragma unroll
        for (int b = 0; b < BC; b++) {
            const float4* hp = (const float4*)&p2_h[b][ks * 16];
            float4 hv0 = hp[0], hv1 = hp[1], hv2 = hp[2], hv3 = hp[3];
            f2 hk2[8] = {{hv0.x, hv0.y}, {hv0.z, hv0.w}, {hv1.x, hv1.y}, {hv1.z, hv1.w},
                         {hv2.x, hv2.y}, {hv2.z, hv2.w}, {hv3.x, hv3.y}, {hv3.z, hv3.w}};
            f2 acc2[4];
#pragma unroll
            for (int g = 0; g < 4; g++) acc2[g] = (f2){0.f, 0.f};
#pragma unroll
            for (int kk = 0; kk < 8; kk++) {
#pragma unroll
                for (int g = 0; g < 4; g++)
                    acc2[g] = fma2(wg2[g][kk], hk2[kk], acc2[g]);
            }
            float a0 = qsum(((ks == 0) ? g1rv[b] : 0.f) + acc2[0].x + acc2[0].y);
            float a1 = qsum(((ks == 1) ? g1rv[b] : 0.f) + acc2[1].x + acc2[1].y);
            float a2 = qsum(((ks == 2) ? g1rv[b] : 0.f) + acc2[2].x + acc2[2].y);
            float a3 = qsum(((ks == 3) ? g1rv[b] : 0.f) + acc2[3].x + acc2[3].y);
            if (ks == b) { myF = a0; myI = a1; myG = a2; myO = a3; }
        }
        {
            float cn = sigm(myF) * cS + sigm(myI) * tanhf(myG);
            cS = cn;
            p2_ht[ks][j] = sigm(myO) * tanhf(cn);
        }
        __syncthreads();
        // ===== C =====
        float z0 = 0, z1 = 0;
#pragma unroll
        for (int b = 0; b < BC; b++) {
            const float4* hp = (const float4*)&p2_ht[b][ks * 16];
            float4 hv0 = hp[0], hv1 = hp[1], hv2 = hp[2], hv3 = hp[3];
            f2 hk2[8] = {{hv0.x, hv0.y}, {hv0.z, hv0.w}, {hv1.x, hv1.y}, {hv1.z, hv1.w},
                         {hv2.x, hv2.y}, {hv2.z, hv2.w}, {hv3.x, hv3.y}, {hv3.z, hv3.w}};
            f2 acc0 = (f2){0.f, 0.f}, acc1 = (f2){0.f, 0.f};
#pragma unroll
            for (int kk = 0; kk < 8; kk++) {
                acc0 = fma2(wm2[0][kk], hk2[kk], acc0);
                acc1 = fma2(wm2[1][kk], hk2[kk], acc1);
            }
            float s0 = (ks == 0) ? h_b1[0] : 0.f;
            float s1 = (ks == 0) ? h_b1[1] : 0.f;
            float a0 = qsum(s0 + acc0.x + acc0.y);
            float a1 = qsum(s1 + acc1.x + acc1.y);
            if (ks == b) { z0 = a0; z1 = a1; }
        }
        {
            int zc = padi(cM);
            p2_z[ks][zc] = gelu_ex(z0);
            p2_z[ks][zc + 1] = gelu_ex(z1);
        }
        __syncthreads();
        // ===== D =====
#pragma unroll
        for (int b = 0; b < BC; b++) {
            const float4* zp = (const float4*)&p2_z[b][ks8 * 20];
            float4 zv0 = zp[0], zv1 = zp[1], zv2 = zp[2], zv3 = zp[3];
            f2 zk2[8] = {{zv0.x, zv0.y}, {zv0.z, zv0.w}, {zv1.x, zv1.y}, {zv1.z, zv1.w},
                         {zv2.x, zv2.y}, {zv2.z, zv2.w}, {zv3.x, zv3.y}, {zv3.z, zv3.w}};
            f2 acc0 = (f2){0.f, 0.f}, acc1 = (f2){0.f, 0.f};
#pragma unroll
            for (int kk = 0; kk < 8; kk++) {
                acc0 = fma2(ww2[0][kk], zk2[kk], acc0);
                acc1 = fma2(ww2[1][kk], zk2[kk], acc1);
            }
            float s0 = (ks8 == 0) ? h_b2[0] : 0.f;
            float s1 = (ks8 == 0) ? h_b2[1] : 0.f;
            float a0 = osum(s0 + acc0.x + acc0.y);
            float a1 = osum(s1 + acc1.x + acc1.y);
            if (ks8 == b) { p2_t2[b][uD] = a0; p2_t2[b][uD + 1] = a1; }
        }
        __syncthreads();
        // ===== E =====
        {
            const int bb = W;
            float r = G1R[(rowBase + (size_t)bb * CT + tt) * 320 + 256 + lane];
            float v = p2_t2[bb][lane];
            float m = redsum64(v) * (1.0f / 64.0f);
            float var = redsum64(v * v) * (1.0f / 64.0f) - m * m;
            float rs = rsqrtf(fmaxf(var, 0.0f) + 1e-5f);
            float a = (v - m) * rs * eLag + eLab;
            float y = a + p2_h[bb][lane];
            float m2 = redsum64(y) * (1.0f / 64.0f);
            float var2 = redsum64(y * y) * (1.0f / 64.0f) - m2 * m2;
            float rs2 = rsqrtf(fmaxf(var2, 0.0f) + 1e-5f);
            float h1n = (y - m2) * rs2 * eLog + eLob;
            p2_h[bb][lane] = h1n;
            merged_c[(((size_t)(sIdx * Bn + gbase + bb)) * CT + tt) * 64 + lane] = f2u(h1n + r);
        }
        __syncthreads();
    }
    {
        int b = tid >> 6, jj = tid & 63;
        gstate[((size_t)(sIdx * Bn + gbase + b)) * 256 + 128 + jj] = p2_h[b][jj];
    }
    gstate[((size_t)(sIdx * Bn + gbase + ks)) * 256 + 192 + j] = cS;
}

// ---------------------------------------------------------------------------
// Fused heavy kernel: blocks [0,384) = pass2(t0_p2); [384,768) = pass1(t0_p1).
// The two halves are data-independent -> 2x resident waves (3 waves/SIMD).
// ---------------------------------------------------------------------------
__global__ __launch_bounds__(256, 2) void fused_kernel(
    const float* __restrict__ x, const float* __restrict__ gw0,
    const float* __restrict__ gb0, const float* __restrict__ gw1,
    const float* __restrict__ M1g, const float* __restrict__ bias1g,
    const float* __restrict__ w2g, const float* __restrict__ b2g,
    const float* __restrict__ lag, const float* __restrict__ lab,
    const float* __restrict__ log_, const float* __restrict__ lob,
    const float* __restrict__ rw0, const float* __restrict__ rb0,
    const float* __restrict__ G1R, float* __restrict__ gstate,
    float* __restrict__ inp_c, unsigned short* __restrict__ merged_c,
    int t0_p2, int t0_p1) {
    if (blockIdx.x < P2BLK) {
        if (t0_p2 < 0) return;
        pass2_body(blockIdx.x, gw1, M1g, bias1g, w2g, b2g, lag, lab, log_, lob,
                   G1R, gstate, merged_c, t0_p2);
    } else {
        if (t0_p1 >= Ln) return;
        pass1_body(blockIdx.x - P2BLK, x, gw0, gb0, M1g, bias1g, w2g, b2g,
                   lag, lab, log_, lob, rw0, rb0, gstate, inp_c, t0_p1);
    }
}

// ---------------------------------------------------------------------------
// g1r body: bid in [0,258)
// ---------------------------------------------------------------------------
__device__ __forceinline__ void g1r_body(
    int bid,
    const float* __restrict__ gw1, const float* __restrict__ gb1,
    const float* __restrict__ rw1, const float* __restrict__ rb1,
    const float* __restrict__ inp_c, float* __restrict__ G1R) {
    const int tid = threadIdx.x;
    const int s = bid / 86;
    const int bb = bid % 86;
    __shared__ __align__(16) float s_W[64 * 320];
    __shared__ __align__(16) float s_inT[64][36];

    for (int i = tid; i < 64 * 64; i += 256) {
        int k = i >> 6, cq = i & 63;
        ((float4*)&s_W[k * 320])[cq] = ((const float4*)(gw1 + (size_t)s * 128 * 256 + k * 256))[cq];
    }
    for (int i = tid; i < 64 * 16; i += 256) {
        int k = i >> 4, cq = i & 15;
        ((float4*)&s_W[k * 320 + 256])[cq] = ((const float4*)(rw1 + (size_t)s * 64 * 64 + k * 64))[cq];
    }
    const int c4 = tid & 63, rg = tid >> 6;
    float4 bias = *(const float4*)(gb1 + s * 256 + c4 * 4);
    float rbias = rb1[s * 64 + c4];

    const size_t sRow = (size_t)s * Bn * CT;
    for (int tile = 0; tile < 6; tile++) {
        int tIdx = bb * 6 + tile;
        if (tIdx >= 512) break;
        int r0 = tIdx * 32;
        __syncthreads();
        for (int i = tid; i < 512; i += 256) {
            int r = i >> 4, kq = i & 15;
            float4 v = *(const float4*)(inp_c + (sRow + r0 + r) * 64 + kq * 4);
            s_inT[kq * 4 + 0][r] = v.x;
            s_inT[kq * 4 + 1][r] = v.y;
            s_inT[kq * 4 + 2][r] = v.z;
            s_inT[kq * 4 + 3][r] = v.w;
        }
        __syncthreads();
        float acc[8][4], accR[8];
#pragma unroll
        for (int r = 0; r < 8; r++) {
            acc[r][0] = bias.x; acc[r][1] = bias.y; acc[r][2] = bias.z; acc[r][3] = bias.w;
            accR[r] = rbias;
        }
        for (int k = 0; k < 64; k++) {
            float4 w = *(const float4*)&s_W[k * 320 + c4 * 4];
            float wR = s_W[k * 320 + 256 + c4];
            float4 iA = *(const float4*)&s_inT[k][rg * 8];
            float4 iB = *(const float4*)&s_inT[k][rg * 8 + 4];
            float in8[8] = {iA.x, iA.y, iA.z, iA.w, iB.x, iB.y, iB.z, iB.w};
#pragma unroll
            for (int r = 0; r < 8; r++) {
                acc[r][0] = fmaf(in8[r], w.x, acc[r][0]);
                acc[r][1] = fmaf(in8[r], w.y, acc[r][1]);
                acc[r][2] = fmaf(in8[r], w.z, acc[r][2]);
                acc[r][3] = fmaf(in8[r], w.w, acc[r][3]);
                accR[r] = fmaf(in8[r], wR, accR[r]);
            }
        }
#pragma unroll
        for (int r = 0; r < 8; r++) {
            size_t row = sRow + r0 + rg * 8 + r;
            float4 o; o.x = acc[r][0]; o.y = acc[r][1]; o.z = acc[r][2]; o.w = acc[r][3];
            *(float4*)(G1R + row * 320 + c4 * 4) = o;
            G1R[row * 320 + 256 + c4] = accR[r];
        }
    }
}

// ---------------------------------------------------------------------------
// combine body: bid in [0,512); each wave handles 8 (b,t) rows
// ---------------------------------------------------------------------------
__device__ __forceinline__ void combine_body(
    int bid,
    const unsigned short* __restrict__ merged_c,
    const float* __restrict__ attn_w,
    void* __restrict__ outv, const int* __restrict__ flag, int t0) {
    int W = threadIdx.x >> 6, lane = threadIdx.x & 63;
    float aw = attn_w[lane];
    size_t stride = (size_t)Bn * CT * 64;
    int isf = *flag;
#pragma unroll
    for (int r = 0; r < 8; r++) {
        int wid = (bid * 4 + W) * 8 + r;
        int b = wid >> 5, tt = wid & 31;
        size_t base = (((size_t)b) * CT + tt) * 64 + lane;
        float m0 = u2f(merged_c[base]);
        float m1 = u2f(merged_c[base + stride]);
        float m2 = u2f(merged_c[base + 2 * stride]);
        float e0 = redsum64(m0 * aw);
        float e1 = redsum64(m1 * aw);
        float e2 = redsum64(m2 * aw);
        float mx = fmaxf(e0, fmaxf(e1, e2));
        float x0 = expf(e0 - mx), x1 = expf(e1 - mx), x2 = expf(e2 - mx);
        float inv = 1.0f / (x0 + x1 + x2);
        float val = (x0 * m0 + x1 * m1 + x2 * m2) * inv;
        size_t ob = (((size_t)b) * Ln + t0 + tt) * 64 + lane;
        if (isf) ((float*)outv)[ob] = val;
        else ((unsigned short*)outv)[ob] = f2u(val);
    }
}

// ---------------------------------------------------------------------------
// Post kernel: blocks [0,258) = g1r (if do_g1r); [258,770) = combine (if t0>=0)
// ---------------------------------------------------------------------------
__global__ __launch_bounds__(256) void postk_kernel(
    const float* __restrict__ gw1, const float* __restrict__ gb1,
    const float* __restrict__ rw1, const float* __restrict__ rb1,
    const float* __restrict__ inp_c, float* __restrict__ G1R, int do_g1r,
    const unsigned short* __restrict__ merged_c, const float* __restrict__ attn_w,
    void* __restrict__ outv, const int* __restrict__ flag, int t0_comb) {
    if (blockIdx.x < G1RBLK) {
        if (do_g1r) g1r_body(blockIdx.x, gw1, gb1, rw1, rb1, inp_c, G1R);
    } else {
        if (t0_comb >= 0)
            combine_body(blockIdx.x - G1RBLK, merged_c, attn_w, outv, flag, t0_comb);
    }
}

extern "C" void kernel_launch(void* const* d_in, const int* in_sizes, int n_in,
                              void* d_out, int out_size, void* d_ws, size_t ws_size,
                              hipStream_t stream) {
    (void)out_size; (void)ws_size;
    int* flag = (int*)d_ws;
    float* canon = (float*)((char*)d_ws + 16);

    ConvArgs ca;
    size_t tot = 0;
    unsigned nblocks = 0;
    for (int i = 0; i < NIN; i++) {
        ca.src[i] = d_in[i];
        ca.dstOff[i] = (unsigned)tot;
        unsigned n = (unsigned)in_sizes[i];
        ca.n[i] = n;
        ca.blockStart[i] = nblocks;
        nblocks += (n + 2047) / 2048;
        tot += n;
    }
    ca.blockStart[NIN] = nblocks;

    size_t canonBytes = (tot * 4 + 15) & ~(size_t)15;
    char* p = (char*)d_ws + 16 + canonBytes;
    float* M1 = (float*)p;       p += (size_t)3 * 2 * 64 * 128 * 4;
    float* bias1 = (float*)p;    p += (size_t)3 * 2 * 128 * 4;
    float* gstate = (float*)p;   p += (size_t)3 * 512 * 4 * 64 * 4;
    float* inp_c = (float*)p;    p += (size_t)3 * 512 * CT * 64 * 4;
    float* G1R = (float*)p;      p += (size_t)3 * 512 * CT * 320 * 4;
    p = (char*)(((uintptr_t)p + 15) & ~(uintptr_t)15);
    unsigned short* merged_c = (unsigned short*)p;

    const float* x    = canon + ca.dstOff[0];
    const float* gw0  = canon + ca.dstOff[1];
    const float* gb0  = canon + ca.dstOff[2];
    const float* gw1  = canon + ca.dstOff[3];
    const float* gb1  = canon + ca.dstOff[4];
    const float* mi_w = canon + ca.dstOff[5];
    const float* mi_b = canon + ca.dstOff[6];
    const float* mo_w = canon + ca.dstOff[7];
    const float* mo_b = canon + ca.dstOff[8];
    const float* w1   = canon + ca.dstOff[9];
    const float* b1   = canon + ca.dstOff[10];
    const float* w2   = canon + ca.dstOff[11];
    const float* b2   = canon + ca.dstOff[12];
    const float* lag  = canon + ca.dstOff[13];
    const float* lab  = canon + ca.dstOff[14];
    const float* log_ = canon + ca.dstOff[15];
    const float* lob  = canon + ca.dstOff[16];
    const float* rw0  = canon + ca.dstOff[17];
    const float* rb0  = canon + ca.dstOff[18];
    const float* rw1  = canon + ca.dstOff[19];
    const float* rb1  = canon + ca.dstOff[20];
    const float* attn_w = canon + ca.dstOff[21];

    detect_kernel<<<dim3(1), dim3(256), 0, stream>>>((const unsigned short*)d_in[0], flag);
    convert_kernel<<<dim3(nblocks), dim3(256), 0, stream>>>(ca, canon, flag);
    fuse_kernel<<<dim3(6), dim3(256), 0, stream>>>(mi_w, mi_b, mo_w, mo_b, w1, b1, M1, bias1);

    // prologue: pass1(0) alone, then g1r(0)
    fused_kernel<<<dim3(2 * P2BLK), dim3(256), 0, stream>>>(
        x, gw0, gb0, gw1, M1, bias1, w2, b2, lag, lab, log_, lob,
        rw0, rb0, G1R, gstate, inp_c, merged_c, -1, 0);
    postk_kernel<<<dim3(G1RBLK + 512), dim3(256), 0, stream>>>(
        gw1, gb1, rw1, rb1, inp_c, G1R, 1, merged_c, attn_w, d_out, flag, -1);

    for (int c = 0; c < NCHUNK; c++) {
        int t0p2 = c * CT;
        int t0p1 = (c + 1) * CT;  // >= Ln on last iteration -> pass1 half skips
        fused_kernel<<<dim3(2 * P2BLK), dim3(256), 0, stream>>>(
            x, gw0, gb0, gw1, M1, bias1, w2, b2, lag, lab, log_, lob,
            rw0, rb0, G1R, gstate, inp_c, merged_c, t0p2, t0p1);
        postk_kernel<<<dim3(G1RBLK + 512), dim3(256), 0, stream>>>(
            gw1, gb1, rw1, rb1, inp_c, G1R, (t0p1 < Ln) ? 1 : 0,
            merged_c, attn_w, d_out, flag, t0p2);
    }
}